// Round 4
// baseline (959.013 us; speedup 1.0000x reference)
//
#include <hip/hip_runtime.h>
#include <hip/hip_bf16.h>
#include <hip/hip_fp16.h>

#define N_NODES 50000
#define N_EDGES 800000
#define ET (N_EDGES + N_NODES)   // edges + self loops = 850000
#define IN_DIM 128
#define F1 256                   // H1*HID
#define H1 4
#define HID 64
#define H2 2
#define OUTC 8
#define F2 16                    // H2*OUTC

typedef unsigned short u16;
typedef unsigned int u32;

static __device__ __forceinline__ float lrelu(float x) { return x > 0.f ? x : 0.2f * x; }
static __device__ __forceinline__ float eluf(float x) { return x > 0.f ? x : __expf(x) - 1.f; }
static __device__ __forceinline__ u16 f2h(float x) {
    __half h = __float2half(x);
    return *reinterpret_cast<u16*>(&h);
}

// ---------------- CSR build ----------------
__global__ void zero_kernel(int* p, int n) {
    int i = blockIdx.x * blockDim.x + threadIdx.x;
    if (i < n) p[i] = 0;
}

// edge_index arrives as int32 (harness converts integer inputs to int32).
__global__ void hist_kernel(const int* __restrict__ ei, int* __restrict__ deg) {
    int e = blockIdx.x * blockDim.x + threadIdx.x;
    if (e >= ET) return;
    int dst = (e < N_EDGES) ? ei[N_EDGES + e] : (e - N_EDGES);
    atomicAdd(&deg[dst], 1);
}

#define SCAN_NT 1024
__global__ __launch_bounds__(SCAN_NT) void scan_kernel(int* __restrict__ deg,
                                                       int* __restrict__ off) {
    __shared__ int sums[SCAN_NT];
    const int ITEMS = (N_NODES + SCAN_NT - 1) / SCAN_NT;  // 49
    int t = threadIdx.x;
    int base = t * ITEMS;
    int s = 0;
    for (int i = 0; i < ITEMS; i++) {
        int idx = base + i;
        if (idx < N_NODES) s += deg[idx];
    }
    sums[t] = s;
    __syncthreads();
    for (int d = 1; d < SCAN_NT; d <<= 1) {
        int v = (t >= d) ? sums[t - d] : 0;
        __syncthreads();
        sums[t] += v;
        __syncthreads();
    }
    int run = (t == 0) ? 0 : sums[t - 1];
    for (int i = 0; i < ITEMS; i++) {
        int idx = base + i;
        if (idx < N_NODES) {
            int v = deg[idx];
            off[idx] = run;
            deg[idx] = run;  // becomes cursor for scatter
            run += v;
        }
    }
    if (t == SCAN_NT - 1) off[N_NODES] = run;
}

__global__ void scatter_kernel(const int* __restrict__ ei, int* __restrict__ cursor,
                               int* __restrict__ csr_src) {
    int e = blockIdx.x * blockDim.x + threadIdx.x;
    if (e >= ET) return;
    int src, dst;
    if (e < N_EDGES) {
        src = ei[e];
        dst = ei[N_EDGES + e];
    } else {
        src = dst = e - N_EDGES;
    }
    int pos = atomicAdd(&cursor[dst], 1);
    csr_src[pos] = src;
}

// ---------------- tiny: transpose 2nd-level weights into WT[50][256] ----------------
// cols 0..15 obj, 16..31 ctx, 32..47 co, 48..49 mlp
__global__ void wt_kernel(const float* __restrict__ W_obj, const float* __restrict__ W_ctx,
                          const float* __restrict__ W_co, const float* __restrict__ W_mlp,
                          float* __restrict__ WT) {
    int t = blockIdx.x * blockDim.x + threadIdx.x;
    if (t >= 50 * 256) return;
    int c = t >> 8;
    int k = t & 255;
    float v;
    if (c < 16) v = W_obj[k * 16 + c];
    else if (c < 32) v = W_ctx[k * 16 + (c - 16)];
    else if (c < 48) v = W_co[k * 16 + (c - 32)];
    else v = W_mlp[k * 2 + (c - 48)];
    WT[c * 256 + k] = v;
}

// ---------------- GEMM1: h_lin = x @ W_feat (fp32 compute), store fp16 interleaved ----------------
// h_fp layout: [node][64 channels][4 heads] fp16  -> per lane one uint2 gather in conv1.
__global__ __launch_bounds__(256) void gemm1_kernel(const float* __restrict__ x,
                                                    const float* __restrict__ Wf,
                                                    const float* __restrict__ a_src,
                                                    const float* __restrict__ a_dst,
                                                    u16* __restrict__ h_fp,
                                                    float* __restrict__ al_s,
                                                    float* __restrict__ al_d) {
    __shared__ float xt[32 * 128];  // 16 KB; reused as fp16 staging (8192 u16) later
    int tid = threadIdx.x;
    int node0 = blockIdx.x * 32;
    const float4* xg = reinterpret_cast<const float4*>(x) + (size_t)node0 * 32;
    float4* xt4 = reinterpret_cast<float4*>(xt);
    int maxf4 = (N_NODES - node0) * 32;
#pragma unroll
    for (int i = 0; i < 4; i++) {
        int f4 = tid + i * 256;
        float4 v = make_float4(0.f, 0.f, 0.f, 0.f);
        if (f4 < maxf4) v = xg[f4];
        xt4[f4] = v;
    }
    __syncthreads();

    float acc[32];
#pragma unroll
    for (int r = 0; r < 32; r++) acc[r] = 0.f;
    int j = tid;
    for (int kc = 0; kc < 128; kc += 8) {
        float w[8];
#pragma unroll
        for (int kk = 0; kk < 8; kk++) w[kk] = Wf[(kc + kk) * 256 + j];
#pragma unroll
        for (int r = 0; r < 32; r++) {
            float4 a0 = xt4[r * 32 + (kc >> 2)];
            float4 a1 = xt4[r * 32 + (kc >> 2) + 1];
            acc[r] += a0.x * w[0] + a0.y * w[1] + a0.z * w[2] + a0.w * w[3] +
                      a1.x * w[4] + a1.y * w[5] + a1.z * w[6] + a1.w * w[7];
        }
    }

    // alpha reductions (register-only): wave w == head w
    {
        int head = tid >> 6;
        int lane = tid & 63;
        float asv = a_src[head * 64 + lane];
        float adv = a_dst[head * 64 + lane];
        for (int r = 0; r < 32; r++) {
            float ps = acc[r] * asv;
            float pd = acc[r] * adv;
#pragma unroll
            for (int d = 1; d < 64; d <<= 1) {
                ps += __shfl_xor(ps, d);
                pd += __shfl_xor(pd, d);
            }
            int node = node0 + r;
            if (lane == 0 && node < N_NODES) {
                al_s[node * 4 + head] = ps;
                al_d[node * 4 + head] = pd;
            }
        }
    }

    // fp16 transpose-staging in LDS: [r][ch][head] u16, then coalesced uint2 copy-out
    __syncthreads();  // done reading xt
    u16* hs = reinterpret_cast<u16*>(xt);
    int headj = tid >> 6, chj = tid & 63;
#pragma unroll
    for (int r = 0; r < 32; r++) hs[r * 256 + chj * 4 + headj] = f2h(acc[r]);
    __syncthreads();
    uint2* hq = reinterpret_cast<uint2*>(h_fp);
    const uint2* hsq = reinterpret_cast<const uint2*>(hs);
#pragma unroll
    for (int it = 0; it < 8; it++) {
        int idx = it * 256 + tid;            // uint2 index within block tile (2048 total)
        int node_local = idx >> 6;           // 64 uint2 per node
        if (node0 + node_local < N_NODES) hq[(size_t)node0 * 64 + idx] = hsq[idx];
    }
}

// ---------------- conv1 aggregation: one wave per dst node ----------------
__global__ __launch_bounds__(256) void conv1_aggregate(const int* __restrict__ deg_off,
                                                       const int* __restrict__ csr_src,
                                                       const u16* __restrict__ h_fp,
                                                       const float* __restrict__ al_s,
                                                       const float* __restrict__ al_d,
                                                       const float* __restrict__ b_feat,
                                                       float* __restrict__ h1) {
    int wave = threadIdx.x >> 6;
    int lane = threadIdx.x & 63;
    int node = blockIdx.x * 4 + wave;
    if (node >= N_NODES) return;
    int beg = deg_off[node], end = deg_off[node + 1];
    float4 aldv = *reinterpret_cast<const float4*>(al_d + node * 4);
    const uint2* hq = reinterpret_cast<const uint2*>(h_fp);
    float acc0 = 0.f, acc1 = 0.f, acc2 = 0.f, acc3 = 0.f;
    float s0 = 0.f, s1 = 0.f, s2 = 0.f, s3 = 0.f;

    int k = beg;
    for (; k + 4 <= end; k += 4) {
        int sa = csr_src[k], sb = csr_src[k + 1], sc = csr_src[k + 2], sd = csr_src[k + 3];
        float4 Aa = *reinterpret_cast<const float4*>(al_s + sa * 4);
        float4 Ab = *reinterpret_cast<const float4*>(al_s + sb * 4);
        float4 Ac = *reinterpret_cast<const float4*>(al_s + sc * 4);
        float4 Ad = *reinterpret_cast<const float4*>(al_s + sd * 4);
        uint2 ha = hq[(size_t)sa * 64 + lane];
        uint2 hb = hq[(size_t)sb * 64 + lane];
        uint2 hc = hq[(size_t)sc * 64 + lane];
        uint2 hd = hq[(size_t)sd * 64 + lane];
#define C1_EDGE(A, h)                                                        \
        {                                                                    \
            float p0 = __expf(lrelu(A.x + aldv.x));                          \
            float p1 = __expf(lrelu(A.y + aldv.y));                          \
            float p2 = __expf(lrelu(A.z + aldv.z));                          \
            float p3 = __expf(lrelu(A.w + aldv.w));                          \
            s0 += p0; s1 += p1; s2 += p2; s3 += p3;                          \
            __half2 q01 = *reinterpret_cast<const __half2*>(&h.x);           \
            __half2 q23 = *reinterpret_cast<const __half2*>(&h.y);           \
            acc0 += p0 * __low2float(q01);                                   \
            acc1 += p1 * __high2float(q01);                                  \
            acc2 += p2 * __low2float(q23);                                   \
            acc3 += p3 * __high2float(q23);                                  \
        }
        C1_EDGE(Aa, ha)
        C1_EDGE(Ab, hb)
        C1_EDGE(Ac, hc)
        C1_EDGE(Ad, hd)
    }
    for (; k < end; k++) {
        int sa = csr_src[k];
        float4 Aa = *reinterpret_cast<const float4*>(al_s + sa * 4);
        uint2 ha = hq[(size_t)sa * 64 + lane];
        C1_EDGE(Aa, ha)
    }
#undef C1_EDGE
    h1[(size_t)node * 256 + 0 * 64 + lane] = eluf(acc0 / (s0 + 1e-16f) + b_feat[0 * 64 + lane]);
    h1[(size_t)node * 256 + 1 * 64 + lane] = eluf(acc1 / (s1 + 1e-16f) + b_feat[1 * 64 + lane]);
    h1[(size_t)node * 256 + 2 * 64 + lane] = eluf(acc2 / (s2 + 1e-16f) + b_feat[2 * 64 + lane]);
    h1[(size_t)node * 256 + 3 * 64 + lane] = eluf(acc3 / (s3 + 1e-16f) + b_feat[3 * 64 + lane]);
}

// ---------------- phase B: wave per node, no LDS ----------------
// lane c<50 computes dot(h1[node], WT[c]); c<48: conv cols (v=c>>4, head=(c>>3)&1, i=c&7);
// c=48,49: node_att mlp logits. Outputs: pack2[node][32 u32] (48 fp16 g + 6 fp32 al_src),
// ald2[node][8] (6 fp32 al_dst), elu(xo)/elu(xc).
__global__ __launch_bounds__(256) void phaseB_kernel(
    const float* __restrict__ h1, const float* __restrict__ WT, const float* __restrict__ b_mlp,
    const float* __restrict__ as_obj, const float* __restrict__ ad_obj,
    const float* __restrict__ as_ctx, const float* __restrict__ ad_ctx,
    const float* __restrict__ as_co, const float* __restrict__ ad_co,
    u32* __restrict__ pack2, float* __restrict__ ald2,
    float* __restrict__ out_xo, float* __restrict__ out_xc) {
    int wave = threadIdx.x >> 6;
    int lane = threadIdx.x & 63;
    int node = blockIdx.x * 4 + wave;
    if (node >= N_NODES) return;
    int c = (lane < 50) ? lane : 0;
    const float4* hrow = reinterpret_cast<const float4*>(h1 + (size_t)node * 256);
    const float4* wrow = reinterpret_cast<const float4*>(WT + c * 256);
    float d0 = 0.f, d1 = 0.f;
#pragma unroll 8
    for (int k4 = 0; k4 < 64; k4 += 2) {
        float4 hv0 = hrow[k4];
        float4 wv0 = wrow[k4];
        float4 hv1 = hrow[k4 + 1];
        float4 wv1 = wrow[k4 + 1];
        d0 += hv0.x * wv0.x + hv0.y * wv0.y + hv0.z * wv0.z + hv0.w * wv0.w;
        d1 += hv1.x * wv1.x + hv1.y * wv1.y + hv1.z * wv1.z + hv1.w * wv1.w;
    }
    float dot = d0 + d1;

    // node_att softmax (redundant on all lanes)
    float l0 = __shfl(dot, 48) + b_mlp[0];
    float l1 = __shfl(dot, 49) + b_mlp[1];
    float mx = fmaxf(l0, l1);
    float e0 = __expf(l0 - mx), e1 = __expf(l1 - mx);
    float inv = 1.f / (e0 + e1);
    float a0 = e0 * inv, a1 = e1 * inv;

    int v = c >> 4, head = (c >> 3) & 1, i = c & 7;
    float scale = (v == 0) ? a0 : ((v == 1) ? a1 : 1.f);
    float g = dot * scale;

    const float* asp = (v == 0) ? as_obj : ((v == 1) ? as_ctx : as_co);
    const float* adp = (v == 0) ? ad_obj : ((v == 1) ? ad_ctx : ad_co);
    float ts = g * asp[head * 8 + i];
    float td = g * adp[head * 8 + i];
#pragma unroll
    for (int d = 1; d < 8; d <<= 1) {
        ts += __shfl_xor(ts, d);
        td += __shfl_xor(td, d);
    }

    // pack fp16 g pairs: even lane packs (g[c], g[c+1])
    float gn = __shfl_xor(g, 1);
    u32* pb = pack2 + (size_t)node * 32;
    if (lane < 48) {
        if ((lane & 1) == 0) {
            __half2 hh = __halves2half2(__float2half(g), __float2half(gn));
            pb[c >> 1] = *reinterpret_cast<u32*>(&hh);
        }
        if (i == 0) {
            int aidx = v * 2 + head;
            pb[24 + aidx] = __float_as_uint(ts);
            ald2[(size_t)node * 8 + aidx] = td;
        }
    }

    // elu outputs: one float4 per lane
    float4 hv = hrow[lane];
    float4 xo4 = make_float4(eluf(a0 * hv.x), eluf(a0 * hv.y), eluf(a0 * hv.z), eluf(a0 * hv.w));
    float4 xc4 = make_float4(eluf(a1 * hv.x), eluf(a1 * hv.y), eluf(a1 * hv.z), eluf(a1 * hv.w));
    reinterpret_cast<float4*>(out_xo + (size_t)node * 256)[lane] = xo4;
    reinterpret_cast<float4*>(out_xc + (size_t)node * 256)[lane] = xc4;
}

// ---------------- fused conv2 aggregation (obj/ctx/co) ----------------
// one wave per dst node; lane = v*16 + head*8 + c (lanes 48..63 duplicate v=2, no writes)
__global__ __launch_bounds__(256) void conv2_aggregate(const int* __restrict__ deg_off,
                                                       const int* __restrict__ csr_src,
                                                       const u32* __restrict__ pack2,
                                                       const float* __restrict__ ald2,
                                                       const float* __restrict__ b_obj,
                                                       const float* __restrict__ b_ctx,
                                                       const float* __restrict__ b_co,
                                                       float* __restrict__ out) {
    int wave = threadIdx.x >> 6;
    int lane = threadIdx.x & 63;
    int node = blockIdx.x * 4 + wave;
    if (node >= N_NODES) return;
    int v = lane >> 4;
    if (v > 2) v = 2;
    int head = (lane >> 3) & 1;
    int c = lane & 7;
    int aidx = v * 2 + head;
    int gword = (v * 16 + head * 8 + c) >> 1;
    int ghi = c & 1;  // which half of the u32
    const float* bb = (v == 0) ? b_obj : (v == 1) ? b_ctx : b_co;
    float ald = ald2[(size_t)node * 8 + aidx];
    int beg = deg_off[node], end = deg_off[node + 1];
    float acc = 0.f, s = 0.f;
    int k = beg;
#define C2_EDGE(sx)                                                              \
    {                                                                            \
        const u32* pb = pack2 + (size_t)(sx) * 32;                               \
        u32 gw = pb[gword];                                                      \
        float als = __uint_as_float(pb[24 + aidx]);                              \
        __half2 gh = *reinterpret_cast<const __half2*>(&gw);                     \
        float g = ghi ? __high2float(gh) : __low2float(gh);                      \
        float p = __expf(lrelu(als + ald));                                      \
        s += p;                                                                  \
        acc += p * g;                                                            \
    }
    for (; k + 4 <= end; k += 4) {
        int sa = csr_src[k], sb = csr_src[k + 1], sc = csr_src[k + 2], sd = csr_src[k + 3];
        C2_EDGE(sa)
        C2_EDGE(sb)
        C2_EDGE(sc)
        C2_EDGE(sd)
    }
    for (; k < end; k++) {
        int sa = csr_src[k];
        C2_EDGE(sa)
    }
#undef C2_EDGE
    float o = acc / (s + 1e-16f);
    float mean = 0.5f * (o + __shfl_xor(o, 8)) + bb[c];
    float mx = mean;
#pragma unroll
    for (int d = 1; d < 8; d <<= 1) mx = fmaxf(mx, __shfl_xor(mx, d));
    float ex = __expf(mean - mx);
    float ss = ex;
#pragma unroll
    for (int d = 1; d < 8; d <<= 1) ss += __shfl_xor(ss, d);
    float res = (mean - mx) - __logf(ss);
    if (lane < 48 && head == 0) out[(size_t)v * (N_NODES * 8) + node * 8 + c] = res;
}

// ---------------- launch ----------------
extern "C" void kernel_launch(void* const* d_in, const int* in_sizes, int n_in, void* d_out,
                              int out_size, void* d_ws, size_t ws_size, hipStream_t stream) {
    const float* x = (const float*)d_in[0];
    const int* ei = (const int*)d_in[1];  // int64 in reference -> int32 from harness
    const float* W_feat = (const float*)d_in[2];
    const float* a_src_feat = (const float*)d_in[3];
    const float* a_dst_feat = (const float*)d_in[4];
    const float* b_feat = (const float*)d_in[5];
    const float* W_mlp = (const float*)d_in[6];
    const float* b_mlp = (const float*)d_in[7];
    const float* W_obj = (const float*)d_in[8];
    const float* as_obj = (const float*)d_in[9];
    const float* ad_obj = (const float*)d_in[10];
    const float* b_obj = (const float*)d_in[11];
    const float* W_ctx = (const float*)d_in[12];
    const float* as_ctx = (const float*)d_in[13];
    const float* ad_ctx = (const float*)d_in[14];
    const float* b_ctx = (const float*)d_in[15];
    const float* W_co = (const float*)d_in[16];
    const float* as_co = (const float*)d_in[17];
    const float* ad_co = (const float*)d_in[18];
    const float* b_co = (const float*)d_in[19];
    float* out = (float*)d_out;

    char* w = (char*)d_ws;
    auto alloc = [&](size_t bytes) {
        void* p = (void*)w;
        w += (bytes + 255) & ~(size_t)255;
        return p;
    };
    int* cursor = (int*)alloc((size_t)N_NODES * 4);
    int* deg_off = (int*)alloc((size_t)(N_NODES + 1) * 4);
    int* csr_src = (int*)alloc((size_t)ET * 4);
    u16* h_fp = (u16*)alloc((size_t)N_NODES * 256 * 2);
    float* al_s1 = (float*)alloc((size_t)N_NODES * 4 * 4);
    float* al_d1 = (float*)alloc((size_t)N_NODES * 4 * 4);
    float* h1 = (float*)alloc((size_t)N_NODES * 256 * 4);
    float* WT = (float*)alloc((size_t)50 * 256 * 4);
    u32* pack2 = (u32*)alloc((size_t)N_NODES * 32 * 4);
    float* ald2 = (float*)alloc((size_t)N_NODES * 8 * 4);

    float* out_xo_logis = out;                       // [N,8] x3 convs
    float* out_xo = out + (size_t)3 * N_NODES * 8;   // [N,256]
    float* out_xc = out_xo + (size_t)N_NODES * 256;  // [N,256]

    // CSR build
    zero_kernel<<<(N_NODES + 255) / 256, 256, 0, stream>>>(cursor, N_NODES);
    hist_kernel<<<(ET + 255) / 256, 256, 0, stream>>>(ei, cursor);
    scan_kernel<<<1, SCAN_NT, 0, stream>>>(cursor, deg_off);
    scatter_kernel<<<(ET + 255) / 256, 256, 0, stream>>>(ei, cursor, csr_src);
    // weight transpose (independent of CSR)
    wt_kernel<<<50, 256, 0, stream>>>(W_obj, W_ctx, W_co, W_mlp, WT);

    // conv1
    gemm1_kernel<<<(N_NODES + 31) / 32, 256, 0, stream>>>(x, W_feat, a_src_feat, a_dst_feat,
                                                          h_fp, al_s1, al_d1);
    conv1_aggregate<<<(N_NODES + 3) / 4, 256, 0, stream>>>(deg_off, csr_src, h_fp, al_s1, al_d1,
                                                           b_feat, h1);
    // phase B
    phaseB_kernel<<<(N_NODES + 3) / 4, 256, 0, stream>>>(
        h1, WT, b_mlp, as_obj, ad_obj, as_ctx, ad_ctx, as_co, ad_co, pack2, ald2, out_xo, out_xc);
    // fused conv2 x3
    conv2_aggregate<<<(N_NODES + 3) / 4, 256, 0, stream>>>(deg_off, csr_src, pack2, ald2, b_obj,
                                                           b_ctx, b_co, out_xo_logis);
}

// Round 5
// 909.167 us; speedup vs baseline: 1.0548x; 1.0548x over previous
//
#include <hip/hip_runtime.h>
#include <hip/hip_bf16.h>
#include <hip/hip_fp16.h>

#define N_NODES 50000
#define N_EDGES 800000
#define ET (N_EDGES + N_NODES)   // edges + self loops = 850000
#define IN_DIM 128
#define F1 256                   // H1*HID
#define H1 4
#define HID 64
#define H2 2
#define OUTC 8
#define F2 16                    // H2*OUTC

typedef unsigned short u16;
typedef unsigned int u32;

static __device__ __forceinline__ float lrelu(float x) { return x > 0.f ? x : 0.2f * x; }
static __device__ __forceinline__ float eluf(float x) { return x > 0.f ? x : __expf(x) - 1.f; }
static __device__ __forceinline__ u16 f2h(float x) {
    __half h = __float2half(x);
    return *reinterpret_cast<u16*>(&h);
}

// ---------------- CSR build ----------------
__global__ void zero_kernel(int* p, int n) {
    int i = blockIdx.x * blockDim.x + threadIdx.x;
    if (i < n) p[i] = 0;
}

// edge_index arrives as int32 (harness converts integer inputs to int32).
__global__ void hist_kernel(const int* __restrict__ ei, int* __restrict__ deg) {
    int e = blockIdx.x * blockDim.x + threadIdx.x;
    if (e >= ET) return;
    int dst = (e < N_EDGES) ? ei[N_EDGES + e] : (e - N_EDGES);
    atomicAdd(&deg[dst], 1);
}

#define SCAN_NT 1024
__global__ __launch_bounds__(SCAN_NT) void scan_kernel(int* __restrict__ deg,
                                                       int* __restrict__ off) {
    __shared__ int sums[SCAN_NT];
    const int ITEMS = (N_NODES + SCAN_NT - 1) / SCAN_NT;  // 49
    int t = threadIdx.x;
    int base = t * ITEMS;
    int s = 0;
    for (int i = 0; i < ITEMS; i++) {
        int idx = base + i;
        if (idx < N_NODES) s += deg[idx];
    }
    sums[t] = s;
    __syncthreads();
    for (int d = 1; d < SCAN_NT; d <<= 1) {
        int v = (t >= d) ? sums[t - d] : 0;
        __syncthreads();
        sums[t] += v;
        __syncthreads();
    }
    int run = (t == 0) ? 0 : sums[t - 1];
    for (int i = 0; i < ITEMS; i++) {
        int idx = base + i;
        if (idx < N_NODES) {
            int v = deg[idx];
            off[idx] = run;
            deg[idx] = run;  // becomes cursor for scatter
            run += v;
        }
    }
    if (t == SCAN_NT - 1) off[N_NODES] = run;
}

__global__ void scatter_kernel(const int* __restrict__ ei, int* __restrict__ cursor,
                               int* __restrict__ csr_src) {
    int e = blockIdx.x * blockDim.x + threadIdx.x;
    if (e >= ET) return;
    int src, dst;
    if (e < N_EDGES) {
        src = ei[e];
        dst = ei[N_EDGES + e];
    } else {
        src = dst = e - N_EDGES;
    }
    int pos = atomicAdd(&cursor[dst], 1);
    csr_src[pos] = src;
}

// ---------------- tiny: transpose 2nd-level weights into WT[50][256] ----------------
// rows 0..15 obj, 16..31 ctx, 32..47 co, 48..49 mlp
__global__ void wt_kernel(const float* __restrict__ W_obj, const float* __restrict__ W_ctx,
                          const float* __restrict__ W_co, const float* __restrict__ W_mlp,
                          float* __restrict__ WT) {
    int t = blockIdx.x * blockDim.x + threadIdx.x;
    if (t >= 50 * 256) return;
    int c = t >> 8;
    int k = t & 255;
    float v;
    if (c < 16) v = W_obj[k * 16 + c];
    else if (c < 32) v = W_ctx[k * 16 + (c - 16)];
    else if (c < 48) v = W_co[k * 16 + (c - 32)];
    else v = W_mlp[k * 2 + (c - 48)];
    WT[c * 256 + k] = v;
}

// ---------------- GEMM1: h_lin = x @ W_feat (fp32 compute), store fp16 interleaved ----------------
// h_fp layout: [node][64 channels][4 heads] fp16  -> per lane one uint2 gather in conv1.
__global__ __launch_bounds__(256) void gemm1_kernel(const float* __restrict__ x,
                                                    const float* __restrict__ Wf,
                                                    const float* __restrict__ a_src,
                                                    const float* __restrict__ a_dst,
                                                    u16* __restrict__ h_fp,
                                                    float* __restrict__ al_s,
                                                    float* __restrict__ al_d) {
    __shared__ float xt[32 * 128];  // 16 KB; reused as fp16 staging (8192 u16) later
    int tid = threadIdx.x;
    int node0 = blockIdx.x * 32;
    const float4* xg = reinterpret_cast<const float4*>(x) + (size_t)node0 * 32;
    float4* xt4 = reinterpret_cast<float4*>(xt);
    int maxf4 = (N_NODES - node0) * 32;
#pragma unroll
    for (int i = 0; i < 4; i++) {
        int f4 = tid + i * 256;
        float4 v = make_float4(0.f, 0.f, 0.f, 0.f);
        if (f4 < maxf4) v = xg[f4];
        xt4[f4] = v;
    }
    __syncthreads();

    float acc[32];
#pragma unroll
    for (int r = 0; r < 32; r++) acc[r] = 0.f;
    int j = tid;
    for (int kc = 0; kc < 128; kc += 8) {
        float w[8];
#pragma unroll
        for (int kk = 0; kk < 8; kk++) w[kk] = Wf[(kc + kk) * 256 + j];
#pragma unroll
        for (int r = 0; r < 32; r++) {
            float4 a0 = xt4[r * 32 + (kc >> 2)];
            float4 a1 = xt4[r * 32 + (kc >> 2) + 1];
            acc[r] += a0.x * w[0] + a0.y * w[1] + a0.z * w[2] + a0.w * w[3] +
                      a1.x * w[4] + a1.y * w[5] + a1.z * w[6] + a1.w * w[7];
        }
    }

    // alpha reductions (register-only): wave w == head w
    {
        int head = tid >> 6;
        int lane = tid & 63;
        float asv = a_src[head * 64 + lane];
        float adv = a_dst[head * 64 + lane];
        for (int r = 0; r < 32; r++) {
            float ps = acc[r] * asv;
            float pd = acc[r] * adv;
#pragma unroll
            for (int d = 1; d < 64; d <<= 1) {
                ps += __shfl_xor(ps, d);
                pd += __shfl_xor(pd, d);
            }
            int node = node0 + r;
            if (lane == 0 && node < N_NODES) {
                al_s[node * 4 + head] = ps;
                al_d[node * 4 + head] = pd;
            }
        }
    }

    // fp16 transpose-staging in LDS: [r][ch][head] u16, then coalesced uint2 copy-out
    __syncthreads();  // done reading xt
    u16* hs = reinterpret_cast<u16*>(xt);
    int headj = tid >> 6, chj = tid & 63;
#pragma unroll
    for (int r = 0; r < 32; r++) hs[r * 256 + chj * 4 + headj] = f2h(acc[r]);
    __syncthreads();
    uint2* hq = reinterpret_cast<uint2*>(h_fp);
    const uint2* hsq = reinterpret_cast<const uint2*>(hs);
#pragma unroll
    for (int it = 0; it < 8; it++) {
        int idx = it * 256 + tid;            // uint2 index within block tile (2048 total)
        int node_local = idx >> 6;           // 64 uint2 per node
        if (node0 + node_local < N_NODES) hq[(size_t)node0 * 64 + idx] = hsq[idx];
    }
}

// ---------------- conv1 aggregation: one wave per dst node ----------------
__global__ __launch_bounds__(256) void conv1_aggregate(const int* __restrict__ deg_off,
                                                       const int* __restrict__ csr_src,
                                                       const u16* __restrict__ h_fp,
                                                       const float* __restrict__ al_s,
                                                       const float* __restrict__ al_d,
                                                       const float* __restrict__ b_feat,
                                                       float* __restrict__ h1) {
    int wave = threadIdx.x >> 6;
    int lane = threadIdx.x & 63;
    int node = blockIdx.x * 4 + wave;
    if (node >= N_NODES) return;
    int beg = deg_off[node], end = deg_off[node + 1];
    float4 aldv = *reinterpret_cast<const float4*>(al_d + node * 4);
    const uint2* hq = reinterpret_cast<const uint2*>(h_fp);
    float acc0 = 0.f, acc1 = 0.f, acc2 = 0.f, acc3 = 0.f;
    float s0 = 0.f, s1 = 0.f, s2 = 0.f, s3 = 0.f;

    int k = beg;
    for (; k + 4 <= end; k += 4) {
        int sa = csr_src[k], sb = csr_src[k + 1], sc = csr_src[k + 2], sd = csr_src[k + 3];
        float4 Aa = *reinterpret_cast<const float4*>(al_s + sa * 4);
        float4 Ab = *reinterpret_cast<const float4*>(al_s + sb * 4);
        float4 Ac = *reinterpret_cast<const float4*>(al_s + sc * 4);
        float4 Ad = *reinterpret_cast<const float4*>(al_s + sd * 4);
        uint2 ha = hq[(size_t)sa * 64 + lane];
        uint2 hb = hq[(size_t)sb * 64 + lane];
        uint2 hc = hq[(size_t)sc * 64 + lane];
        uint2 hd = hq[(size_t)sd * 64 + lane];
#define C1_EDGE(A, h)                                                        \
        {                                                                    \
            float p0 = __expf(lrelu(A.x + aldv.x));                          \
            float p1 = __expf(lrelu(A.y + aldv.y));                          \
            float p2 = __expf(lrelu(A.z + aldv.z));                          \
            float p3 = __expf(lrelu(A.w + aldv.w));                          \
            s0 += p0; s1 += p1; s2 += p2; s3 += p3;                          \
            __half2 q01 = *reinterpret_cast<const __half2*>(&h.x);           \
            __half2 q23 = *reinterpret_cast<const __half2*>(&h.y);           \
            acc0 += p0 * __low2float(q01);                                   \
            acc1 += p1 * __high2float(q01);                                  \
            acc2 += p2 * __low2float(q23);                                   \
            acc3 += p3 * __high2float(q23);                                  \
        }
        C1_EDGE(Aa, ha)
        C1_EDGE(Ab, hb)
        C1_EDGE(Ac, hc)
        C1_EDGE(Ad, hd)
    }
    for (; k < end; k++) {
        int sa = csr_src[k];
        float4 Aa = *reinterpret_cast<const float4*>(al_s + sa * 4);
        uint2 ha = hq[(size_t)sa * 64 + lane];
        C1_EDGE(Aa, ha)
    }
#undef C1_EDGE
    h1[(size_t)node * 256 + 0 * 64 + lane] = eluf(acc0 / (s0 + 1e-16f) + b_feat[0 * 64 + lane]);
    h1[(size_t)node * 256 + 1 * 64 + lane] = eluf(acc1 / (s1 + 1e-16f) + b_feat[1 * 64 + lane]);
    h1[(size_t)node * 256 + 2 * 64 + lane] = eluf(acc2 / (s2 + 1e-16f) + b_feat[2 * 64 + lane]);
    h1[(size_t)node * 256 + 3 * 64 + lane] = eluf(acc3 / (s3 + 1e-16f) + b_feat[3 * 64 + lane]);
}

// ---------------- phase B: 32-node tile, LDS h (padded), parallel epilogue ----------------
// dots[r][c]: c 0..47 conv cols (obj/ctx/co x16), 48..49 mlp logits, 50..51 a0/a1.
#define RSTR 260  // h-tile row stride in floats (pad +4 -> conflict-free ds_read_b128)
__global__ __launch_bounds__(256) void phaseB_kernel(
    const float* __restrict__ h1, const float* __restrict__ WT, const float* __restrict__ b_mlp,
    const float* __restrict__ as_obj, const float* __restrict__ ad_obj,
    const float* __restrict__ as_ctx, const float* __restrict__ ad_ctx,
    const float* __restrict__ as_co, const float* __restrict__ ad_co,
    u32* __restrict__ pack2, float* __restrict__ ald2,
    float* __restrict__ out_xo, float* __restrict__ out_xc) {
    __shared__ float ht[32 * RSTR];   // 33.3 KB
    __shared__ float dots[32][56];    // 7.2 KB
    int tid = threadIdx.x;
    int node0 = blockIdx.x * 32;
    float4* ht4 = reinterpret_cast<float4*>(ht);
    const float4* hg = reinterpret_cast<const float4*>(h1) + (size_t)node0 * 64;
    int maxf4 = (N_NODES - node0) * 64;
#pragma unroll
    for (int i = 0; i < 8; i++) {
        int idx = tid + i * 256;       // 0..2047
        int r = idx >> 6, c4 = idx & 63;
        float4 v = make_float4(0.f, 0.f, 0.f, 0.f);
        if (idx < maxf4) v = hg[idx];
        ht4[r * (RSTR / 4) + c4] = v;
    }
    __syncthreads();

    // dot phase: 416 tasks = 32 nodes x 13 col-groups; task jj<12 -> cols 4jj..4jj+3, jj=12 -> 48,49
    const float4* WT4 = reinterpret_cast<const float4*>(WT);
    for (int t = tid; t < 32 * 13; t += 256) {
        int r = t / 13;
        int jj = t - r * 13;
        int c0 = jj * 4;
        int ncols = (jj < 12) ? 4 : 2;
        float ax0 = 0.f, ax1 = 0.f, ax2 = 0.f, ax3 = 0.f;
        for (int k4 = 0; k4 < 64; k4++) {
            float4 hv = ht4[r * (RSTR / 4) + k4];
            float4 w0 = WT4[(c0 + 0) * 64 + k4];
            float4 w1 = WT4[(c0 + 1) * 64 + k4];
            ax0 += hv.x * w0.x + hv.y * w0.y + hv.z * w0.z + hv.w * w0.w;
            ax1 += hv.x * w1.x + hv.y * w1.y + hv.z * w1.z + hv.w * w1.w;
            if (ncols == 4) {
                float4 w2 = WT4[(c0 + 2) * 64 + k4];
                float4 w3 = WT4[(c0 + 3) * 64 + k4];
                ax2 += hv.x * w2.x + hv.y * w2.y + hv.z * w2.z + hv.w * w2.w;
                ax3 += hv.x * w3.x + hv.y * w3.y + hv.z * w3.z + hv.w * w3.w;
            }
        }
        dots[r][c0 + 0] = ax0;
        dots[r][c0 + 1] = ax1;
        if (ncols == 4) {
            dots[r][c0 + 2] = ax2;
            dots[r][c0 + 3] = ax3;
        }
    }
    __syncthreads();

    // epilogue A: node_att softmax (32 threads, ~10 ops each)
    if (tid < 32) {
        int r = tid;
        float l0 = dots[r][48] + b_mlp[0];
        float l1 = dots[r][49] + b_mlp[1];
        float mx = fmaxf(l0, l1);
        float e0 = __expf(l0 - mx), e1 = __expf(l1 - mx);
        float inv = 1.f / (e0 + e1);
        dots[r][50] = e0 * inv;
        dots[r][51] = e1 * inv;
    }
    __syncthreads();

    // epilogue B: 8 threads per node -> fp16 pack (3 words each) + alpha sums (j<6)
    {
        int r = tid >> 3, j = tid & 7;
        int node = node0 + r;
        if (node < N_NODES) {
            float a0 = dots[r][50], a1 = dots[r][51];
            u32* pb = pack2 + (size_t)node * 32;
#pragma unroll
            for (int wi = 0; wi < 3; wi++) {
                int w = j + wi * 8;        // word 0..23
                int c0 = 2 * w;
                int v = c0 >> 4;
                float scale = (v == 0) ? a0 : ((v == 1) ? a1 : 1.f);
                float g0 = dots[r][c0] * scale;
                float g1 = dots[r][c0 + 1] * scale;
                __half2 hh = __halves2half2(__float2half(g0), __float2half(g1));
                pb[w] = *reinterpret_cast<u32*>(&hh);
            }
            if (j < 6) {
                int v = j >> 1, head = j & 1;
                float scale = (v == 0) ? a0 : ((v == 1) ? a1 : 1.f);
                const float* asp = (v == 0) ? as_obj : ((v == 1) ? as_ctx : as_co);
                const float* adp = (v == 0) ? ad_obj : ((v == 1) ? ad_ctx : ad_co);
                float ss = 0.f, dd = 0.f;
#pragma unroll
                for (int i = 0; i < 8; i++) {
                    float g = dots[r][v * 16 + head * 8 + i] * scale;
                    ss += g * asp[head * 8 + i];
                    dd += g * adp[head * 8 + i];
                }
                pb[24 + j] = __float_as_uint(ss);
                ald2[(size_t)node * 8 + j] = dd;
            }
        }
    }

    // epilogue C: elu outputs, coalesced (no barrier needed: reads ht + dots[..][50,51] only)
    {
        int c = tid;
        for (int r = 0; r < 32; r++) {
            int node = node0 + r;
            if (node >= N_NODES) break;
            float a0 = dots[r][50], a1 = dots[r][51];
            float hv = ht[r * RSTR + c];
            out_xo[(size_t)node * 256 + c] = eluf(a0 * hv);
            out_xc[(size_t)node * 256 + c] = eluf(a1 * hv);
        }
    }
}

// ---------------- fused conv2 aggregation (obj/ctx/co) ----------------
// one wave per dst node; lane = v*16 + head*8 + c (lanes 48..63 duplicate v=2, no writes)
__global__ __launch_bounds__(256) void conv2_aggregate(const int* __restrict__ deg_off,
                                                       const int* __restrict__ csr_src,
                                                       const u32* __restrict__ pack2,
                                                       const float* __restrict__ ald2,
                                                       const float* __restrict__ b_obj,
                                                       const float* __restrict__ b_ctx,
                                                       const float* __restrict__ b_co,
                                                       float* __restrict__ out) {
    int wave = threadIdx.x >> 6;
    int lane = threadIdx.x & 63;
    int node = blockIdx.x * 4 + wave;
    if (node >= N_NODES) return;
    int v = lane >> 4;
    if (v > 2) v = 2;
    int head = (lane >> 3) & 1;
    int c = lane & 7;
    int aidx = v * 2 + head;
    int gword = (v * 16 + head * 8 + c) >> 1;
    int ghi = c & 1;  // which half of the u32
    const float* bb = (v == 0) ? b_obj : (v == 1) ? b_ctx : b_co;
    float ald = ald2[(size_t)node * 8 + aidx];
    int beg = deg_off[node], end = deg_off[node + 1];
    float acc = 0.f, s = 0.f;
    int k = beg;
#define C2_EDGE(sx)                                                              \
    {                                                                            \
        const u32* pb = pack2 + (size_t)(sx) * 32;                               \
        u32 gw = pb[gword];                                                      \
        float als = __uint_as_float(pb[24 + aidx]);                              \
        __half2 gh = *reinterpret_cast<const __half2*>(&gw);                     \
        float g = ghi ? __high2float(gh) : __low2float(gh);                      \
        float p = __expf(lrelu(als + ald));                                      \
        s += p;                                                                  \
        acc += p * g;                                                            \
    }
    for (; k + 4 <= end; k += 4) {
        int sa = csr_src[k], sb = csr_src[k + 1], sc = csr_src[k + 2], sd = csr_src[k + 3];
        C2_EDGE(sa)
        C2_EDGE(sb)
        C2_EDGE(sc)
        C2_EDGE(sd)
    }
    for (; k < end; k++) {
        int sa = csr_src[k];
        C2_EDGE(sa)
    }
#undef C2_EDGE
    float o = acc / (s + 1e-16f);
    float mean = 0.5f * (o + __shfl_xor(o, 8)) + bb[c];
    float mx = mean;
#pragma unroll
    for (int d = 1; d < 8; d <<= 1) mx = fmaxf(mx, __shfl_xor(mx, d));
    float ex = __expf(mean - mx);
    float ss = ex;
#pragma unroll
    for (int d = 1; d < 8; d <<= 1) ss += __shfl_xor(ss, d);
    float res = (mean - mx) - __logf(ss);
    if (lane < 48 && head == 0) out[(size_t)v * (N_NODES * 8) + node * 8 + c] = res;
}

// ---------------- launch ----------------
extern "C" void kernel_launch(void* const* d_in, const int* in_sizes, int n_in, void* d_out,
                              int out_size, void* d_ws, size_t ws_size, hipStream_t stream) {
    const float* x = (const float*)d_in[0];
    const int* ei = (const int*)d_in[1];  // int64 in reference -> int32 from harness
    const float* W_feat = (const float*)d_in[2];
    const float* a_src_feat = (const float*)d_in[3];
    const float* a_dst_feat = (const float*)d_in[4];
    const float* b_feat = (const float*)d_in[5];
    const float* W_mlp = (const float*)d_in[6];
    const float* b_mlp = (const float*)d_in[7];
    const float* W_obj = (const float*)d_in[8];
    const float* as_obj = (const float*)d_in[9];
    const float* ad_obj = (const float*)d_in[10];
    const float* b_obj = (const float*)d_in[11];
    const float* W_ctx = (const float*)d_in[12];
    const float* as_ctx = (const float*)d_in[13];
    const float* ad_ctx = (const float*)d_in[14];
    const float* b_ctx = (const float*)d_in[15];
    const float* W_co = (const float*)d_in[16];
    const float* as_co = (const float*)d_in[17];
    const float* ad_co = (const float*)d_in[18];
    const float* b_co = (const float*)d_in[19];
    float* out = (float*)d_out;

    char* w = (char*)d_ws;
    auto alloc = [&](size_t bytes) {
        void* p = (void*)w;
        w += (bytes + 255) & ~(size_t)255;
        return p;
    };
    int* cursor = (int*)alloc((size_t)N_NODES * 4);
    int* deg_off = (int*)alloc((size_t)(N_NODES + 1) * 4);
    int* csr_src = (int*)alloc((size_t)ET * 4);
    u16* h_fp = (u16*)alloc((size_t)N_NODES * 256 * 2);
    float* al_s1 = (float*)alloc((size_t)N_NODES * 4 * 4);
    float* al_d1 = (float*)alloc((size_t)N_NODES * 4 * 4);
    float* h1 = (float*)alloc((size_t)N_NODES * 256 * 4);
    float* WT = (float*)alloc((size_t)50 * 256 * 4);
    u32* pack2 = (u32*)alloc((size_t)N_NODES * 32 * 4);
    float* ald2 = (float*)alloc((size_t)N_NODES * 8 * 4);

    float* out_xo_logis = out;                       // [N,8] x3 convs
    float* out_xo = out + (size_t)3 * N_NODES * 8;   // [N,256]
    float* out_xc = out_xo + (size_t)N_NODES * 256;  // [N,256]

    // CSR build
    zero_kernel<<<(N_NODES + 255) / 256, 256, 0, stream>>>(cursor, N_NODES);
    hist_kernel<<<(ET + 255) / 256, 256, 0, stream>>>(ei, cursor);
    scan_kernel<<<1, SCAN_NT, 0, stream>>>(cursor, deg_off);
    scatter_kernel<<<(ET + 255) / 256, 256, 0, stream>>>(ei, cursor, csr_src);
    // weight transpose (independent of CSR)
    wt_kernel<<<50, 256, 0, stream>>>(W_obj, W_ctx, W_co, W_mlp, WT);

    // conv1
    gemm1_kernel<<<(N_NODES + 31) / 32, 256, 0, stream>>>(x, W_feat, a_src_feat, a_dst_feat,
                                                          h_fp, al_s1, al_d1);
    conv1_aggregate<<<(N_NODES + 3) / 4, 256, 0, stream>>>(deg_off, csr_src, h_fp, al_s1, al_d1,
                                                           b_feat, h1);
    // phase B
    phaseB_kernel<<<(N_NODES + 31) / 32, 256, 0, stream>>>(
        h1, WT, b_mlp, as_obj, ad_obj, as_ctx, ad_ctx, as_co, ad_co, pack2, ald2, out_xo, out_xc);
    // fused conv2 x3
    conv2_aggregate<<<(N_NODES + 3) / 4, 256, 0, stream>>>(deg_off, csr_src, pack2, ald2, b_obj,
                                                           b_ctx, b_co, out_xo_logis);
}

// Round 6
// 701.562 us; speedup vs baseline: 1.3670x; 1.2959x over previous
//
#include <hip/hip_runtime.h>
#include <hip/hip_bf16.h>
#include <hip/hip_fp16.h>

#define N_NODES 50000
#define N_EDGES 800000
#define ET (N_EDGES + N_NODES)   // edges + self loops = 850000
#define IN_DIM 128
#define F1 256                   // H1*HID
#define H1 4
#define HID 64
#define H2 2
#define OUTC 8
#define F2 16                    // H2*OUTC

typedef unsigned short u16;
typedef unsigned int u32;

static __device__ __forceinline__ float lrelu(float x) { return x > 0.f ? x : 0.2f * x; }
static __device__ __forceinline__ float eluf(float x) { return x > 0.f ? x : __expf(x) - 1.f; }
static __device__ __forceinline__ u16 f2h(float x) {
    __half h = __float2half(x);
    return *reinterpret_cast<u16*>(&h);
}

// ---------------- CSR build ----------------
__global__ void zero_kernel(int* p, int n) {
    int i = blockIdx.x * blockDim.x + threadIdx.x;
    if (i < n) p[i] = 0;
}

// edge_index arrives as int32 (harness converts integer inputs to int32).
__global__ void hist_kernel(const int* __restrict__ ei, int* __restrict__ deg) {
    int e = blockIdx.x * blockDim.x + threadIdx.x;
    if (e >= ET) return;
    int dst = (e < N_EDGES) ? ei[N_EDGES + e] : (e - N_EDGES);
    atomicAdd(&deg[dst], 1);
}

#define SCAN_NT 1024
__global__ __launch_bounds__(SCAN_NT) void scan_kernel(int* __restrict__ deg,
                                                       int* __restrict__ off) {
    __shared__ int sums[SCAN_NT];
    const int ITEMS = (N_NODES + SCAN_NT - 1) / SCAN_NT;  // 49
    int t = threadIdx.x;
    int base = t * ITEMS;
    int s = 0;
    for (int i = 0; i < ITEMS; i++) {
        int idx = base + i;
        if (idx < N_NODES) s += deg[idx];
    }
    sums[t] = s;
    __syncthreads();
    for (int d = 1; d < SCAN_NT; d <<= 1) {
        int v = (t >= d) ? sums[t - d] : 0;
        __syncthreads();
        sums[t] += v;
        __syncthreads();
    }
    int run = (t == 0) ? 0 : sums[t - 1];
    for (int i = 0; i < ITEMS; i++) {
        int idx = base + i;
        if (idx < N_NODES) {
            int v = deg[idx];
            off[idx] = run;
            deg[idx] = run;  // becomes cursor for scatter
            run += v;
        }
    }
    if (t == SCAN_NT - 1) off[N_NODES] = run;
}

__global__ void scatter_kernel(const int* __restrict__ ei, int* __restrict__ cursor,
                               int* __restrict__ csr_src) {
    int e = blockIdx.x * blockDim.x + threadIdx.x;
    if (e >= ET) return;
    int src, dst;
    if (e < N_EDGES) {
        src = ei[e];
        dst = ei[N_EDGES + e];
    } else {
        src = dst = e - N_EDGES;
    }
    int pos = atomicAdd(&cursor[dst], 1);
    csr_src[pos] = src;
}

// ---------------- tiny: interleave 2nd-level weights into WTi[k4][64][4] ----------------
// col c: 0..15 obj, 16..31 ctx, 32..47 co, 48..49 mlp, 50..63 zero-pad.
// float4 at WTi4[k4*64 + c] = (W[4k4][c], W[4k4+1][c], W[4k4+2][c], W[4k4+3][c])
__global__ void wt_kernel(const float* __restrict__ W_obj, const float* __restrict__ W_ctx,
                          const float* __restrict__ W_co, const float* __restrict__ W_mlp,
                          float* __restrict__ WTi) {
    int t = blockIdx.x * blockDim.x + threadIdx.x;
    if (t >= 64 * 256) return;
    int c = t >> 8;
    int k = t & 255;
    float v = 0.f;
    if (c < 16) v = W_obj[k * 16 + c];
    else if (c < 32) v = W_ctx[k * 16 + (c - 16)];
    else if (c < 48) v = W_co[k * 16 + (c - 32)];
    else if (c < 50) v = W_mlp[k * 2 + (c - 48)];
    WTi[(k >> 2) * 256 + c * 4 + (k & 3)] = v;
}

// ---------------- GEMM1: h_lin = x @ W_feat (fp32 compute), store fp16 interleaved ----------------
// h_fp layout: [node][64 channels][4 heads] fp16  -> per lane one uint2 gather in conv1.
__global__ __launch_bounds__(256) void gemm1_kernel(const float* __restrict__ x,
                                                    const float* __restrict__ Wf,
                                                    const float* __restrict__ a_src,
                                                    const float* __restrict__ a_dst,
                                                    u16* __restrict__ h_fp,
                                                    float* __restrict__ al_s,
                                                    float* __restrict__ al_d) {
    __shared__ float xt[32 * 128];  // 16 KB; reused as fp16 staging (8192 u16) later
    int tid = threadIdx.x;
    int node0 = blockIdx.x * 32;
    const float4* xg = reinterpret_cast<const float4*>(x) + (size_t)node0 * 32;
    float4* xt4 = reinterpret_cast<float4*>(xt);
    int maxf4 = (N_NODES - node0) * 32;
#pragma unroll
    for (int i = 0; i < 4; i++) {
        int f4 = tid + i * 256;
        float4 v = make_float4(0.f, 0.f, 0.f, 0.f);
        if (f4 < maxf4) v = xg[f4];
        xt4[f4] = v;
    }
    __syncthreads();

    float acc[32];
#pragma unroll
    for (int r = 0; r < 32; r++) acc[r] = 0.f;
    int j = tid;
    for (int kc = 0; kc < 128; kc += 8) {
        float w[8];
#pragma unroll
        for (int kk = 0; kk < 8; kk++) w[kk] = Wf[(kc + kk) * 256 + j];
#pragma unroll
        for (int r = 0; r < 32; r++) {
            float4 a0 = xt4[r * 32 + (kc >> 2)];
            float4 a1 = xt4[r * 32 + (kc >> 2) + 1];
            acc[r] += a0.x * w[0] + a0.y * w[1] + a0.z * w[2] + a0.w * w[3] +
                      a1.x * w[4] + a1.y * w[5] + a1.z * w[6] + a1.w * w[7];
        }
    }

    // alpha reductions (register-only): wave w == head w
    {
        int head = tid >> 6;
        int lane = tid & 63;
        float asv = a_src[head * 64 + lane];
        float adv = a_dst[head * 64 + lane];
        for (int r = 0; r < 32; r++) {
            float ps = acc[r] * asv;
            float pd = acc[r] * adv;
#pragma unroll
            for (int d = 1; d < 64; d <<= 1) {
                ps += __shfl_xor(ps, d);
                pd += __shfl_xor(pd, d);
            }
            int node = node0 + r;
            if (lane == 0 && node < N_NODES) {
                al_s[node * 4 + head] = ps;
                al_d[node * 4 + head] = pd;
            }
        }
    }

    // fp16 transpose-staging in LDS: [r][ch][head] u16, then coalesced uint2 copy-out
    __syncthreads();  // done reading xt
    u16* hs = reinterpret_cast<u16*>(xt);
    int headj = tid >> 6, chj = tid & 63;
#pragma unroll
    for (int r = 0; r < 32; r++) hs[r * 256 + chj * 4 + headj] = f2h(acc[r]);
    __syncthreads();
    uint2* hq = reinterpret_cast<uint2*>(h_fp);
    const uint2* hsq = reinterpret_cast<const uint2*>(hs);
#pragma unroll
    for (int it = 0; it < 8; it++) {
        int idx = it * 256 + tid;            // uint2 index within block tile (2048 total)
        int node_local = idx >> 6;           // 64 uint2 per node
        if (node0 + node_local < N_NODES) hq[(size_t)node0 * 64 + idx] = hsq[idx];
    }
}

// ---------------- conv1 aggregation: one wave per dst node ----------------
__global__ __launch_bounds__(256) void conv1_aggregate(const int* __restrict__ deg_off,
                                                       const int* __restrict__ csr_src,
                                                       const u16* __restrict__ h_fp,
                                                       const float* __restrict__ al_s,
                                                       const float* __restrict__ al_d,
                                                       const float* __restrict__ b_feat,
                                                       float* __restrict__ h1) {
    int wave = threadIdx.x >> 6;
    int lane = threadIdx.x & 63;
    int node = blockIdx.x * 4 + wave;
    if (node >= N_NODES) return;
    int beg = deg_off[node], end = deg_off[node + 1];
    float4 aldv = *reinterpret_cast<const float4*>(al_d + node * 4);
    const uint2* hq = reinterpret_cast<const uint2*>(h_fp);
    float acc0 = 0.f, acc1 = 0.f, acc2 = 0.f, acc3 = 0.f;
    float s0 = 0.f, s1 = 0.f, s2 = 0.f, s3 = 0.f;

    int k = beg;
    for (; k + 4 <= end; k += 4) {
        int sa = csr_src[k], sb = csr_src[k + 1], sc = csr_src[k + 2], sd = csr_src[k + 3];
        float4 Aa = *reinterpret_cast<const float4*>(al_s + sa * 4);
        float4 Ab = *reinterpret_cast<const float4*>(al_s + sb * 4);
        float4 Ac = *reinterpret_cast<const float4*>(al_s + sc * 4);
        float4 Ad = *reinterpret_cast<const float4*>(al_s + sd * 4);
        uint2 ha = hq[(size_t)sa * 64 + lane];
        uint2 hb = hq[(size_t)sb * 64 + lane];
        uint2 hc = hq[(size_t)sc * 64 + lane];
        uint2 hd = hq[(size_t)sd * 64 + lane];
#define C1_EDGE(A, h)                                                        \
        {                                                                    \
            float p0 = __expf(lrelu(A.x + aldv.x));                          \
            float p1 = __expf(lrelu(A.y + aldv.y));                          \
            float p2 = __expf(lrelu(A.z + aldv.z));                          \
            float p3 = __expf(lrelu(A.w + aldv.w));                          \
            s0 += p0; s1 += p1; s2 += p2; s3 += p3;                          \
            __half2 q01 = *reinterpret_cast<const __half2*>(&h.x);           \
            __half2 q23 = *reinterpret_cast<const __half2*>(&h.y);           \
            acc0 += p0 * __low2float(q01);                                   \
            acc1 += p1 * __high2float(q01);                                  \
            acc2 += p2 * __low2float(q23);                                   \
            acc3 += p3 * __high2float(q23);                                  \
        }
        C1_EDGE(Aa, ha)
        C1_EDGE(Ab, hb)
        C1_EDGE(Ac, hc)
        C1_EDGE(Ad, hd)
    }
    for (; k < end; k++) {
        int sa = csr_src[k];
        float4 Aa = *reinterpret_cast<const float4*>(al_s + sa * 4);
        uint2 ha = hq[(size_t)sa * 64 + lane];
        C1_EDGE(Aa, ha)
    }
#undef C1_EDGE
    h1[(size_t)node * 256 + 0 * 64 + lane] = eluf(acc0 / (s0 + 1e-16f) + b_feat[0 * 64 + lane]);
    h1[(size_t)node * 256 + 1 * 64 + lane] = eluf(acc1 / (s1 + 1e-16f) + b_feat[1 * 64 + lane]);
    h1[(size_t)node * 256 + 2 * 64 + lane] = eluf(acc2 / (s2 + 1e-16f) + b_feat[2 * 64 + lane]);
    h1[(size_t)node * 256 + 3 * 64 + lane] = eluf(acc3 / (s3 + 1e-16f) + b_feat[3 * 64 + lane]);
}

// ---------------- phase B v3: lane=column (coalesced W), wave=8 nodes (broadcast h) ----------------
// dots[r][c]: c 0..47 conv cols (obj/ctx/co x16), 48..49 mlp logits, 50..51 a0/a1.
__global__ __launch_bounds__(256) void phaseB_kernel(
    const float* __restrict__ h1, const float* __restrict__ WTi, const float* __restrict__ b_mlp,
    const float* __restrict__ as_obj, const float* __restrict__ ad_obj,
    const float* __restrict__ as_ctx, const float* __restrict__ ad_ctx,
    const float* __restrict__ as_co, const float* __restrict__ ad_co,
    u32* __restrict__ pack2, float* __restrict__ ald2,
    float* __restrict__ out_xo, float* __restrict__ out_xc) {
    __shared__ float dots[32][52];  // 6.6 KB
    int tid = threadIdx.x;
    int node0 = blockIdx.x * 32;
    int lane = tid & 63;   // column
    int rg = tid >> 6;     // wave: nodes rg*8 .. rg*8+7
    const float4* WTi4 = reinterpret_cast<const float4*>(WTi);
    const float4* hg = reinterpret_cast<const float4*>(h1) + (size_t)node0 * 64;

    float accd[8];
#pragma unroll
    for (int r = 0; r < 8; r++) accd[r] = 0.f;
    // (last block: rows beyond N read garbage from adjacent ws region; never written out)
#pragma unroll 2
    for (int k4 = 0; k4 < 64; k4++) {
        float4 wv = WTi4[k4 * 64 + lane];          // coalesced 1KB/wave, L2-hot
#pragma unroll
        for (int r = 0; r < 8; r++) {
            float4 hv = hg[(rg * 8 + r) * 64 + k4]; // wave-uniform broadcast load
            accd[r] += hv.x * wv.x + hv.y * wv.y + hv.z * wv.z + hv.w * wv.w;
        }
    }
    if (lane < 50) {
#pragma unroll
        for (int r = 0; r < 8; r++) dots[rg * 8 + r][lane] = accd[r];
    }
    __syncthreads();

    // epilogue A: node_att softmax (32 threads)
    if (tid < 32) {
        int r = tid;
        float l0 = dots[r][48] + b_mlp[0];
        float l1 = dots[r][49] + b_mlp[1];
        float mx = fmaxf(l0, l1);
        float e0 = __expf(l0 - mx), e1 = __expf(l1 - mx);
        float inv = 1.f / (e0 + e1);
        dots[r][50] = e0 * inv;
        dots[r][51] = e1 * inv;
    }
    __syncthreads();

    // epilogue B: 8 threads per node -> fp16 pack (3 words each) + alpha sums (j<6)
    {
        int r = tid >> 3, j = tid & 7;
        int node = node0 + r;
        if (node < N_NODES) {
            float a0 = dots[r][50], a1 = dots[r][51];
            u32* pb = pack2 + (size_t)node * 32;
#pragma unroll
            for (int wi = 0; wi < 3; wi++) {
                int w = j + wi * 8;        // word 0..23
                int c0 = 2 * w;
                int v = c0 >> 4;
                float scale = (v == 0) ? a0 : ((v == 1) ? a1 : 1.f);
                float g0 = dots[r][c0] * scale;
                float g1 = dots[r][c0 + 1] * scale;
                __half2 hh = __halves2half2(__float2half(g0), __float2half(g1));
                pb[w] = *reinterpret_cast<u32*>(&hh);
            }
            if (j < 6) {
                int v = j >> 1, head = j & 1;
                float scale = (v == 0) ? a0 : ((v == 1) ? a1 : 1.f);
                const float* asp = (v == 0) ? as_obj : ((v == 1) ? as_ctx : as_co);
                const float* adp = (v == 0) ? ad_obj : ((v == 1) ? ad_ctx : ad_co);
                float ss = 0.f, dd = 0.f;
#pragma unroll
                for (int i = 0; i < 8; i++) {
                    float g = dots[r][v * 16 + head * 8 + i] * scale;
                    ss += g * asp[head * 8 + i];
                    dd += g * adp[head * 8 + i];
                }
                pb[24 + j] = __float_as_uint(ss);
                ald2[(size_t)node * 8 + j] = dd;
            }
        }
    }

    // epilogue C: elu outputs, float4 coalesced (h1 re-read from global, L2-hot)
    {
#pragma unroll
        for (int i = 0; i < 8; i++) {
            int idx = tid + i * 256;       // 0..2047
            int r = idx >> 6, c4 = idx & 63;
            int node = node0 + r;
            if (node < N_NODES) {
                float4 hv = hg[idx];
                float a0 = dots[r][50], a1 = dots[r][51];
                float4 xo4 = make_float4(eluf(a0 * hv.x), eluf(a0 * hv.y),
                                         eluf(a0 * hv.z), eluf(a0 * hv.w));
                float4 xc4 = make_float4(eluf(a1 * hv.x), eluf(a1 * hv.y),
                                         eluf(a1 * hv.z), eluf(a1 * hv.w));
                reinterpret_cast<float4*>(out_xo + (size_t)node * 256)[c4] = xo4;
                reinterpret_cast<float4*>(out_xc + (size_t)node * 256)[c4] = xc4;
            }
        }
    }
}

// ---------------- fused conv2 aggregation (obj/ctx/co) ----------------
// one wave per dst node; lane = v*16 + head*8 + c (lanes 48..63 duplicate v=2, no writes)
__global__ __launch_bounds__(256) void conv2_aggregate(const int* __restrict__ deg_off,
                                                       const int* __restrict__ csr_src,
                                                       const u32* __restrict__ pack2,
                                                       const float* __restrict__ ald2,
                                                       const float* __restrict__ b_obj,
                                                       const float* __restrict__ b_ctx,
                                                       const float* __restrict__ b_co,
                                                       float* __restrict__ out) {
    int wave = threadIdx.x >> 6;
    int lane = threadIdx.x & 63;
    int node = blockIdx.x * 4 + wave;
    if (node >= N_NODES) return;
    int v = lane >> 4;
    if (v > 2) v = 2;
    int head = (lane >> 3) & 1;
    int c = lane & 7;
    int aidx = v * 2 + head;
    int gword = (v * 16 + head * 8 + c) >> 1;
    int ghi = c & 1;  // which half of the u32
    const float* bb = (v == 0) ? b_obj : (v == 1) ? b_ctx : b_co;
    float ald = ald2[(size_t)node * 8 + aidx];
    int beg = deg_off[node], end = deg_off[node + 1];
    float acc = 0.f, s = 0.f;
    int k = beg;
#define C2_EDGE(sx)                                                              \
    {                                                                            \
        const u32* pb = pack2 + (size_t)(sx) * 32;                               \
        u32 gw = pb[gword];                                                      \
        float als = __uint_as_float(pb[24 + aidx]);                              \
        __half2 gh = *reinterpret_cast<const __half2*>(&gw);                     \
        float g = ghi ? __high2float(gh) : __low2float(gh);                      \
        float p = __expf(lrelu(als + ald));                                      \
        s += p;                                                                  \
        acc += p * g;                                                            \
    }
    for (; k + 4 <= end; k += 4) {
        int sa = csr_src[k], sb = csr_src[k + 1], sc = csr_src[k + 2], sd = csr_src[k + 3];
        C2_EDGE(sa)
        C2_EDGE(sb)
        C2_EDGE(sc)
        C2_EDGE(sd)
    }
    for (; k < end; k++) {
        int sa = csr_src[k];
        C2_EDGE(sa)
    }
#undef C2_EDGE
    float o = acc / (s + 1e-16f);
    float mean = 0.5f * (o + __shfl_xor(o, 8)) + bb[c];
    float mx = mean;
#pragma unroll
    for (int d = 1; d < 8; d <<= 1) mx = fmaxf(mx, __shfl_xor(mx, d));
    float ex = __expf(mean - mx);
    float ss = ex;
#pragma unroll
    for (int d = 1; d < 8; d <<= 1) ss += __shfl_xor(ss, d);
    float res = (mean - mx) - __logf(ss);
    if (lane < 48 && head == 0) out[(size_t)v * (N_NODES * 8) + node * 8 + c] = res;
}

// ---------------- launch ----------------
extern "C" void kernel_launch(void* const* d_in, const int* in_sizes, int n_in, void* d_out,
                              int out_size, void* d_ws, size_t ws_size, hipStream_t stream) {
    const float* x = (const float*)d_in[0];
    const int* ei = (const int*)d_in[1];  // int64 in reference -> int32 from harness
    const float* W_feat = (const float*)d_in[2];
    const float* a_src_feat = (const float*)d_in[3];
    const float* a_dst_feat = (const float*)d_in[4];
    const float* b_feat = (const float*)d_in[5];
    const float* W_mlp = (const float*)d_in[6];
    const float* b_mlp = (const float*)d_in[7];
    const float* W_obj = (const float*)d_in[8];
    const float* as_obj = (const float*)d_in[9];
    const float* ad_obj = (const float*)d_in[10];
    const float* b_obj = (const float*)d_in[11];
    const float* W_ctx = (const float*)d_in[12];
    const float* as_ctx = (const float*)d_in[13];
    const float* ad_ctx = (const float*)d_in[14];
    const float* b_ctx = (const float*)d_in[15];
    const float* W_co = (const float*)d_in[16];
    const float* as_co = (const float*)d_in[17];
    const float* ad_co = (const float*)d_in[18];
    const float* b_co = (const float*)d_in[19];
    float* out = (float*)d_out;

    char* w = (char*)d_ws;
    auto alloc = [&](size_t bytes) {
        void* p = (void*)w;
        w += (bytes + 255) & ~(size_t)255;
        return p;
    };
    int* cursor = (int*)alloc((size_t)N_NODES * 4);
    int* deg_off = (int*)alloc((size_t)(N_NODES + 1) * 4);
    int* csr_src = (int*)alloc((size_t)ET * 4);
    u16* h_fp = (u16*)alloc((size_t)N_NODES * 256 * 2);
    float* al_s1 = (float*)alloc((size_t)N_NODES * 4 * 4);
    float* al_d1 = (float*)alloc((size_t)N_NODES * 4 * 4);
    float* h1 = (float*)alloc((size_t)N_NODES * 256 * 4);
    float* WTi = (float*)alloc((size_t)64 * 256 * 4);
    u32* pack2 = (u32*)alloc((size_t)N_NODES * 32 * 4);
    float* ald2 = (float*)alloc((size_t)N_NODES * 8 * 4);

    float* out_xo_logis = out;                       // [N,8] x3 convs
    float* out_xo = out + (size_t)3 * N_NODES * 8;   // [N,256]
    float* out_xc = out_xo + (size_t)N_NODES * 256;  // [N,256]

    // CSR build
    zero_kernel<<<(N_NODES + 255) / 256, 256, 0, stream>>>(cursor, N_NODES);
    hist_kernel<<<(ET + 255) / 256, 256, 0, stream>>>(ei, cursor);
    scan_kernel<<<1, SCAN_NT, 0, stream>>>(cursor, deg_off);
    scatter_kernel<<<(ET + 255) / 256, 256, 0, stream>>>(ei, cursor, csr_src);
    // weight interleave (independent of CSR)
    wt_kernel<<<64, 256, 0, stream>>>(W_obj, W_ctx, W_co, W_mlp, WTi);

    // conv1
    gemm1_kernel<<<(N_NODES + 31) / 32, 256, 0, stream>>>(x, W_feat, a_src_feat, a_dst_feat,
                                                          h_fp, al_s1, al_d1);
    conv1_aggregate<<<(N_NODES + 3) / 4, 256, 0, stream>>>(deg_off, csr_src, h_fp, al_s1, al_d1,
                                                           b_feat, h1);
    // phase B
    phaseB_kernel<<<(N_NODES + 31) / 32, 256, 0, stream>>>(
        h1, WTi, b_mlp, as_obj, ad_obj, as_ctx, ad_ctx, as_co, ad_co, pack2, ald2, out_xo, out_xc);
    // fused conv2 x3
    conv2_aggregate<<<(N_NODES + 3) / 4, 256, 0, stream>>>(deg_off, csr_src, pack2, ald2, b_obj,
                                                           b_ctx, b_co, out_xo_logis);
}

// Round 7
// 630.184 us; speedup vs baseline: 1.5218x; 1.1133x over previous
//
#include <hip/hip_runtime.h>
#include <hip/hip_bf16.h>
#include <hip/hip_fp16.h>

#define N_NODES 50000
#define N_EDGES 800000
#define ET (N_EDGES + N_NODES)   // edges + self loops = 850000
#define IN_DIM 128
#define F1 256                   // H1*HID
#define H1 4
#define HID 64
#define H2 2
#define OUTC 8
#define F2 16                    // H2*OUTC

typedef unsigned short u16;
typedef unsigned int u32;

static __device__ __forceinline__ float lrelu(float x) { return x > 0.f ? x : 0.2f * x; }
static __device__ __forceinline__ float eluf(float x) { return x > 0.f ? x : __expf(x) - 1.f; }
static __device__ __forceinline__ u16 f2h(float x) {
    __half h = __float2half(x);
    return *reinterpret_cast<u16*>(&h);
}

// ---------------- CSR build ----------------
__global__ void zero_kernel(int* p, int n) {
    int i = blockIdx.x * blockDim.x + threadIdx.x;
    if (i < n) p[i] = 0;
}

// edge_index arrives as int32 (harness converts integer inputs to int32).
__global__ void hist_kernel(const int* __restrict__ ei, int* __restrict__ deg) {
    int e = blockIdx.x * blockDim.x + threadIdx.x;
    if (e >= ET) return;
    int dst = (e < N_EDGES) ? ei[N_EDGES + e] : (e - N_EDGES);
    atomicAdd(&deg[dst], 1);
}

#define SCAN_NT 1024
__global__ __launch_bounds__(SCAN_NT) void scan_kernel(int* __restrict__ deg,
                                                       int* __restrict__ off) {
    __shared__ int sums[SCAN_NT];
    const int ITEMS = (N_NODES + SCAN_NT - 1) / SCAN_NT;  // 49
    int t = threadIdx.x;
    int base = t * ITEMS;
    int s = 0;
    for (int i = 0; i < ITEMS; i++) {
        int idx = base + i;
        if (idx < N_NODES) s += deg[idx];
    }
    sums[t] = s;
    __syncthreads();
    for (int d = 1; d < SCAN_NT; d <<= 1) {
        int v = (t >= d) ? sums[t - d] : 0;
        __syncthreads();
        sums[t] += v;
        __syncthreads();
    }
    int run = (t == 0) ? 0 : sums[t - 1];
    for (int i = 0; i < ITEMS; i++) {
        int idx = base + i;
        if (idx < N_NODES) {
            int v = deg[idx];
            off[idx] = run;
            deg[idx] = run;  // becomes cursor for scatter
            run += v;
        }
    }
    if (t == SCAN_NT - 1) off[N_NODES] = run;
}

__global__ void scatter_kernel(const int* __restrict__ ei, int* __restrict__ cursor,
                               int* __restrict__ csr_src) {
    int e = blockIdx.x * blockDim.x + threadIdx.x;
    if (e >= ET) return;
    int src, dst;
    if (e < N_EDGES) {
        src = ei[e];
        dst = ei[N_EDGES + e];
    } else {
        src = dst = e - N_EDGES;
    }
    int pos = atomicAdd(&cursor[dst], 1);
    csr_src[pos] = src;
}

// ---------------- tiny: interleave 2nd-level weights into WTi[k4][64][4] ----------------
// col c: 0..15 obj, 16..31 ctx, 32..47 co, 48..49 mlp, 50..63 zero-pad.
// float4 at WTi4[k4*64 + c] = (W[4k4][c], W[4k4+1][c], W[4k4+2][c], W[4k4+3][c])
__global__ void wt_kernel(const float* __restrict__ W_obj, const float* __restrict__ W_ctx,
                          const float* __restrict__ W_co, const float* __restrict__ W_mlp,
                          float* __restrict__ WTi) {
    int t = blockIdx.x * blockDim.x + threadIdx.x;
    if (t >= 64 * 256) return;
    int c = t >> 8;
    int k = t & 255;
    float v = 0.f;
    if (c < 16) v = W_obj[k * 16 + c];
    else if (c < 32) v = W_ctx[k * 16 + (c - 16)];
    else if (c < 48) v = W_co[k * 16 + (c - 32)];
    else if (c < 50) v = W_mlp[k * 2 + (c - 48)];
    WTi[(k >> 2) * 256 + c * 4 + (k & 3)] = v;
}

// ---------------- GEMM1: h_lin = x @ W_feat (fp32 compute), store fp16 interleaved ----------------
// h_fp layout: [node][64 channels][4 heads] fp16  -> per lane one uint2 gather in conv1.
__global__ __launch_bounds__(256) void gemm1_kernel(const float* __restrict__ x,
                                                    const float* __restrict__ Wf,
                                                    const float* __restrict__ a_src,
                                                    const float* __restrict__ a_dst,
                                                    u16* __restrict__ h_fp,
                                                    float* __restrict__ al_s,
                                                    float* __restrict__ al_d) {
    __shared__ float xt[32 * 128];  // 16 KB; reused as fp16 staging (8192 u16) later
    int tid = threadIdx.x;
    int node0 = blockIdx.x * 32;
    const float4* xg = reinterpret_cast<const float4*>(x) + (size_t)node0 * 32;
    float4* xt4 = reinterpret_cast<float4*>(xt);
    int maxf4 = (N_NODES - node0) * 32;
#pragma unroll
    for (int i = 0; i < 4; i++) {
        int f4 = tid + i * 256;
        float4 v = make_float4(0.f, 0.f, 0.f, 0.f);
        if (f4 < maxf4) v = xg[f4];
        xt4[f4] = v;
    }
    __syncthreads();

    float acc[32];
#pragma unroll
    for (int r = 0; r < 32; r++) acc[r] = 0.f;
    int j = tid;
    for (int kc = 0; kc < 128; kc += 8) {
        float w[8];
#pragma unroll
        for (int kk = 0; kk < 8; kk++) w[kk] = Wf[(kc + kk) * 256 + j];
#pragma unroll
        for (int r = 0; r < 32; r++) {
            float4 a0 = xt4[r * 32 + (kc >> 2)];
            float4 a1 = xt4[r * 32 + (kc >> 2) + 1];
            acc[r] += a0.x * w[0] + a0.y * w[1] + a0.z * w[2] + a0.w * w[3] +
                      a1.x * w[4] + a1.y * w[5] + a1.z * w[6] + a1.w * w[7];
        }
    }

    // alpha reductions (register-only): wave w == head w
    {
        int head = tid >> 6;
        int lane = tid & 63;
        float asv = a_src[head * 64 + lane];
        float adv = a_dst[head * 64 + lane];
        for (int r = 0; r < 32; r++) {
            float ps = acc[r] * asv;
            float pd = acc[r] * adv;
#pragma unroll
            for (int d = 1; d < 64; d <<= 1) {
                ps += __shfl_xor(ps, d);
                pd += __shfl_xor(pd, d);
            }
            int node = node0 + r;
            if (lane == 0 && node < N_NODES) {
                al_s[node * 4 + head] = ps;
                al_d[node * 4 + head] = pd;
            }
        }
    }

    // fp16 transpose-staging in LDS: [r][ch][head] u16, then coalesced uint2 copy-out
    __syncthreads();  // done reading xt
    u16* hs = reinterpret_cast<u16*>(xt);
    int headj = tid >> 6, chj = tid & 63;
#pragma unroll
    for (int r = 0; r < 32; r++) hs[r * 256 + chj * 4 + headj] = f2h(acc[r]);
    __syncthreads();
    uint2* hq = reinterpret_cast<uint2*>(h_fp);
    const uint2* hsq = reinterpret_cast<const uint2*>(hs);
#pragma unroll
    for (int it = 0; it < 8; it++) {
        int idx = it * 256 + tid;            // uint2 index within block tile (2048 total)
        int node_local = idx >> 6;           // 64 uint2 per node
        if (node0 + node_local < N_NODES) hq[(size_t)node0 * 64 + idx] = hsq[idx];
    }
}

// ---------------- conv1 aggregation: one wave per dst node ----------------
__global__ __launch_bounds__(256) void conv1_aggregate(const int* __restrict__ deg_off,
                                                       const int* __restrict__ csr_src,
                                                       const u16* __restrict__ h_fp,
                                                       const float* __restrict__ al_s,
                                                       const float* __restrict__ al_d,
                                                       const float* __restrict__ b_feat,
                                                       float* __restrict__ h1) {
    int wave = threadIdx.x >> 6;
    int lane = threadIdx.x & 63;
    int node = blockIdx.x * 4 + wave;
    if (node >= N_NODES) return;
    int beg = deg_off[node], end = deg_off[node + 1];
    float4 aldv = *reinterpret_cast<const float4*>(al_d + node * 4);
    const uint2* hq = reinterpret_cast<const uint2*>(h_fp);
    float acc0 = 0.f, acc1 = 0.f, acc2 = 0.f, acc3 = 0.f;
    float s0 = 0.f, s1 = 0.f, s2 = 0.f, s3 = 0.f;

    int k = beg;
    for (; k + 4 <= end; k += 4) {
        int sa = csr_src[k], sb = csr_src[k + 1], sc = csr_src[k + 2], sd = csr_src[k + 3];
        float4 Aa = *reinterpret_cast<const float4*>(al_s + sa * 4);
        float4 Ab = *reinterpret_cast<const float4*>(al_s + sb * 4);
        float4 Ac = *reinterpret_cast<const float4*>(al_s + sc * 4);
        float4 Ad = *reinterpret_cast<const float4*>(al_s + sd * 4);
        uint2 ha = hq[(size_t)sa * 64 + lane];
        uint2 hb = hq[(size_t)sb * 64 + lane];
        uint2 hc = hq[(size_t)sc * 64 + lane];
        uint2 hd = hq[(size_t)sd * 64 + lane];
#define C1_EDGE(A, h)                                                        \
        {                                                                    \
            float p0 = __expf(lrelu(A.x + aldv.x));                          \
            float p1 = __expf(lrelu(A.y + aldv.y));                          \
            float p2 = __expf(lrelu(A.z + aldv.z));                          \
            float p3 = __expf(lrelu(A.w + aldv.w));                          \
            s0 += p0; s1 += p1; s2 += p2; s3 += p3;                          \
            __half2 q01 = *reinterpret_cast<const __half2*>(&h.x);           \
            __half2 q23 = *reinterpret_cast<const __half2*>(&h.y);           \
            acc0 += p0 * __low2float(q01);                                   \
            acc1 += p1 * __high2float(q01);                                  \
            acc2 += p2 * __low2float(q23);                                   \
            acc3 += p3 * __high2float(q23);                                  \
        }
        C1_EDGE(Aa, ha)
        C1_EDGE(Ab, hb)
        C1_EDGE(Ac, hc)
        C1_EDGE(Ad, hd)
    }
    for (; k < end; k++) {
        int sa = csr_src[k];
        float4 Aa = *reinterpret_cast<const float4*>(al_s + sa * 4);
        uint2 ha = hq[(size_t)sa * 64 + lane];
        C1_EDGE(Aa, ha)
    }
#undef C1_EDGE
    h1[(size_t)node * 256 + 0 * 64 + lane] = eluf(acc0 / (s0 + 1e-16f) + b_feat[0 * 64 + lane]);
    h1[(size_t)node * 256 + 1 * 64 + lane] = eluf(acc1 / (s1 + 1e-16f) + b_feat[1 * 64 + lane]);
    h1[(size_t)node * 256 + 2 * 64 + lane] = eluf(acc2 / (s2 + 1e-16f) + b_feat[2 * 64 + lane]);
    h1[(size_t)node * 256 + 3 * 64 + lane] = eluf(acc3 / (s3 + 1e-16f) + b_feat[3 * 64 + lane]);
}

// ---------------- phase B v4: h tile staged in LDS; lane=column (coalesced W) ----------------
// dots[r][c]: c 0..47 conv cols (obj/ctx/co x16), 48..49 mlp logits, 50..51 a0/a1.
__global__ __launch_bounds__(256) void phaseB_kernel(
    const float* __restrict__ h1, const float* __restrict__ WTi, const float* __restrict__ b_mlp,
    const float* __restrict__ as_obj, const float* __restrict__ ad_obj,
    const float* __restrict__ as_ctx, const float* __restrict__ ad_ctx,
    const float* __restrict__ as_co, const float* __restrict__ ad_co,
    u32* __restrict__ pack2, float* __restrict__ ald2,
    float* __restrict__ out_xo, float* __restrict__ out_xc) {
    __shared__ float hts[32 * 256];  // 32 KB h tile
    __shared__ float dots[32][52];   // 6.6 KB
    int tid = threadIdx.x;
    int node0 = blockIdx.x * 32;
    int lane = tid & 63;   // column
    int rg = tid >> 6;     // wave: nodes rg*8 .. rg*8+7
    const float4* WTi4 = reinterpret_cast<const float4*>(WTi);
    const float4* hg = reinterpret_cast<const float4*>(h1) + (size_t)node0 * 64;
    float4* hts4 = reinterpret_cast<float4*>(hts);

    // stage h tile: fully coalesced, 8 independent float4 loads per thread
    int maxf4 = (N_NODES - node0) * 64;
#pragma unroll
    for (int i = 0; i < 8; i++) {
        int idx = tid + i * 256;  // 0..2047
        float4 v = make_float4(0.f, 0.f, 0.f, 0.f);
        if (idx < maxf4) v = hg[idx];
        hts4[idx] = v;
    }
    __syncthreads();

    float accd[8];
#pragma unroll
    for (int r = 0; r < 8; r++) accd[r] = 0.f;
#pragma unroll 2
    for (int k4 = 0; k4 < 64; k4++) {
        float4 wv = WTi4[k4 * 64 + lane];           // coalesced 1KB/wave, L1/L2-hot
#pragma unroll
        for (int r = 0; r < 8; r++) {
            float4 hv = hts4[(rg * 8 + r) * 64 + k4];  // LDS broadcast (uniform addr)
            accd[r] += hv.x * wv.x + hv.y * wv.y + hv.z * wv.z + hv.w * wv.w;
        }
    }
    if (lane < 50) {
#pragma unroll
        for (int r = 0; r < 8; r++) dots[rg * 8 + r][lane] = accd[r];
    }
    __syncthreads();

    // epilogue A: node_att softmax (32 threads)
    if (tid < 32) {
        int r = tid;
        float l0 = dots[r][48] + b_mlp[0];
        float l1 = dots[r][49] + b_mlp[1];
        float mx = fmaxf(l0, l1);
        float e0 = __expf(l0 - mx), e1 = __expf(l1 - mx);
        float inv = 1.f / (e0 + e1);
        dots[r][50] = e0 * inv;
        dots[r][51] = e1 * inv;
    }
    __syncthreads();

    // epilogue B: 8 threads per node -> fp16 pack (3 words each) + alpha sums (j<6)
    {
        int r = tid >> 3, j = tid & 7;
        int node = node0 + r;
        if (node < N_NODES) {
            float a0 = dots[r][50], a1 = dots[r][51];
            u32* pb = pack2 + (size_t)node * 32;
#pragma unroll
            for (int wi = 0; wi < 3; wi++) {
                int w = j + wi * 8;        // word 0..23
                int c0 = 2 * w;
                int v = c0 >> 4;
                float scale = (v == 0) ? a0 : ((v == 1) ? a1 : 1.f);
                float g0 = dots[r][c0] * scale;
                float g1 = dots[r][c0 + 1] * scale;
                __half2 hh = __halves2half2(__float2half(g0), __float2half(g1));
                pb[w] = *reinterpret_cast<u32*>(&hh);
            }
            if (j < 6) {
                int v = j >> 1, head = j & 1;
                float scale = (v == 0) ? a0 : ((v == 1) ? a1 : 1.f);
                const float* asp = (v == 0) ? as_obj : ((v == 1) ? as_ctx : as_co);
                const float* adp = (v == 0) ? ad_obj : ((v == 1) ? ad_ctx : ad_co);
                float ss = 0.f, dd = 0.f;
#pragma unroll
                for (int i = 0; i < 8; i++) {
                    float g = dots[r][v * 16 + head * 8 + i] * scale;
                    ss += g * asp[head * 8 + i];
                    dd += g * adp[head * 8 + i];
                }
                pb[24 + j] = __float_as_uint(ss);
                ald2[(size_t)node * 8 + j] = dd;
            }
        }
    }
    __syncthreads();

    // epilogue C: elu outputs from LDS, float4 coalesced writes
    {
#pragma unroll
        for (int i = 0; i < 8; i++) {
            int idx = tid + i * 256;       // 0..2047
            int r = idx >> 6, c4 = idx & 63;
            int node = node0 + r;
            if (node < N_NODES) {
                float4 hv = hts4[idx];
                float a0 = dots[r][50], a1 = dots[r][51];
                float4 xo4 = make_float4(eluf(a0 * hv.x), eluf(a0 * hv.y),
                                         eluf(a0 * hv.z), eluf(a0 * hv.w));
                float4 xc4 = make_float4(eluf(a1 * hv.x), eluf(a1 * hv.y),
                                         eluf(a1 * hv.z), eluf(a1 * hv.w));
                reinterpret_cast<float4*>(out_xo + (size_t)node * 256)[c4] = xo4;
                reinterpret_cast<float4*>(out_xc + (size_t)node * 256)[c4] = xc4;
            }
        }
    }
}

// ---------------- fused conv2 aggregation (obj/ctx/co) ----------------
// one wave per dst node; lane = v*16 + head*8 + c (lanes 48..63 duplicate v=2, no writes)
__global__ __launch_bounds__(256) void conv2_aggregate(const int* __restrict__ deg_off,
                                                       const int* __restrict__ csr_src,
                                                       const u32* __restrict__ pack2,
                                                       const float* __restrict__ ald2,
                                                       const float* __restrict__ b_obj,
                                                       const float* __restrict__ b_ctx,
                                                       const float* __restrict__ b_co,
                                                       float* __restrict__ out) {
    int wave = threadIdx.x >> 6;
    int lane = threadIdx.x & 63;
    int node = blockIdx.x * 4 + wave;
    if (node >= N_NODES) return;
    int v = lane >> 4;
    if (v > 2) v = 2;
    int head = (lane >> 3) & 1;
    int c = lane & 7;
    int aidx = v * 2 + head;
    int gword = (v * 16 + head * 8 + c) >> 1;
    int ghi = c & 1;  // which half of the u32
    const float* bb = (v == 0) ? b_obj : (v == 1) ? b_ctx : b_co;
    float ald = ald2[(size_t)node * 8 + aidx];
    int beg = deg_off[node], end = deg_off[node + 1];
    float acc = 0.f, s = 0.f;
    int k = beg;
#define C2_EDGE(sx)                                                              \
    {                                                                            \
        const u32* pb = pack2 + (size_t)(sx) * 32;                               \
        u32 gw = pb[gword];                                                      \
        float als = __uint_as_float(pb[24 + aidx]);                              \
        __half2 gh = *reinterpret_cast<const __half2*>(&gw);                     \
        float g = ghi ? __high2float(gh) : __low2float(gh);                      \
        float p = __expf(lrelu(als + ald));                                      \
        s += p;                                                                  \
        acc += p * g;                                                            \
    }
    for (; k + 4 <= end; k += 4) {
        int sa = csr_src[k], sb = csr_src[k + 1], sc = csr_src[k + 2], sd = csr_src[k + 3];
        C2_EDGE(sa)
        C2_EDGE(sb)
        C2_EDGE(sc)
        C2_EDGE(sd)
    }
    for (; k < end; k++) {
        int sa = csr_src[k];
        C2_EDGE(sa)
    }
#undef C2_EDGE
    float o = acc / (s + 1e-16f);
    float mean = 0.5f * (o + __shfl_xor(o, 8)) + bb[c];
    float mx = mean;
#pragma unroll
    for (int d = 1; d < 8; d <<= 1) mx = fmaxf(mx, __shfl_xor(mx, d));
    float ex = __expf(mean - mx);
    float ss = ex;
#pragma unroll
    for (int d = 1; d < 8; d <<= 1) ss += __shfl_xor(ss, d);
    float res = (mean - mx) - __logf(ss);
    if (lane < 48 && head == 0) out[(size_t)v * (N_NODES * 8) + node * 8 + c] = res;
}

// ---------------- launch ----------------
extern "C" void kernel_launch(void* const* d_in, const int* in_sizes, int n_in, void* d_out,
                              int out_size, void* d_ws, size_t ws_size, hipStream_t stream) {
    const float* x = (const float*)d_in[0];
    const int* ei = (const int*)d_in[1];  // int64 in reference -> int32 from harness
    const float* W_feat = (const float*)d_in[2];
    const float* a_src_feat = (const float*)d_in[3];
    const float* a_dst_feat = (const float*)d_in[4];
    const float* b_feat = (const float*)d_in[5];
    const float* W_mlp = (const float*)d_in[6];
    const float* b_mlp = (const float*)d_in[7];
    const float* W_obj = (const float*)d_in[8];
    const float* as_obj = (const float*)d_in[9];
    const float* ad_obj = (const float*)d_in[10];
    const float* b_obj = (const float*)d_in[11];
    const float* W_ctx = (const float*)d_in[12];
    const float* as_ctx = (const float*)d_in[13];
    const float* ad_ctx = (const float*)d_in[14];
    const float* b_ctx = (const float*)d_in[15];
    const float* W_co = (const float*)d_in[16];
    const float* as_co = (const float*)d_in[17];
    const float* ad_co = (const float*)d_in[18];
    const float* b_co = (const float*)d_in[19];
    float* out = (float*)d_out;

    char* w = (char*)d_ws;
    auto alloc = [&](size_t bytes) {
        void* p = (void*)w;
        w += (bytes + 255) & ~(size_t)255;
        return p;
    };
    int* cursor = (int*)alloc((size_t)N_NODES * 4);
    int* deg_off = (int*)alloc((size_t)(N_NODES + 1) * 4);
    int* csr_src = (int*)alloc((size_t)ET * 4);
    u16* h_fp = (u16*)alloc((size_t)N_NODES * 256 * 2);
    float* al_s1 = (float*)alloc((size_t)N_NODES * 4 * 4);
    float* al_d1 = (float*)alloc((size_t)N_NODES * 4 * 4);
    float* h1 = (float*)alloc((size_t)N_NODES * 256 * 4);
    float* WTi = (float*)alloc((size_t)64 * 256 * 4);
    u32* pack2 = (u32*)alloc((size_t)N_NODES * 32 * 4);
    float* ald2 = (float*)alloc((size_t)N_NODES * 8 * 4);

    float* out_xo_logis = out;                       // [N,8] x3 convs
    float* out_xo = out + (size_t)3 * N_NODES * 8;   // [N,256]
    float* out_xc = out_xo + (size_t)N_NODES * 256;  // [N,256]

    // CSR build
    zero_kernel<<<(N_NODES + 255) / 256, 256, 0, stream>>>(cursor, N_NODES);
    hist_kernel<<<(ET + 255) / 256, 256, 0, stream>>>(ei, cursor);
    scan_kernel<<<1, SCAN_NT, 0, stream>>>(cursor, deg_off);
    scatter_kernel<<<(ET + 255) / 256, 256, 0, stream>>>(ei, cursor, csr_src);
    // weight interleave (independent of CSR)
    wt_kernel<<<64, 256, 0, stream>>>(W_obj, W_ctx, W_co, W_mlp, WTi);

    // conv1
    gemm1_kernel<<<(N_NODES + 31) / 32, 256, 0, stream>>>(x, W_feat, a_src_feat, a_dst_feat,
                                                          h_fp, al_s1, al_d1);
    conv1_aggregate<<<(N_NODES + 3) / 4, 256, 0, stream>>>(deg_off, csr_src, h_fp, al_s1, al_d1,
                                                           b_feat, h1);
    // phase B
    phaseB_kernel<<<(N_NODES + 31) / 32, 256, 0, stream>>>(
        h1, WTi, b_mlp, as_obj, ad_obj, as_ctx, ad_ctx, as_co, ad_co, pack2, ald2, out_xo, out_xc);
    // fused conv2 x3
    conv2_aggregate<<<(N_NODES + 3) / 4, 256, 0, stream>>>(deg_off, csr_src, pack2, ald2, b_obj,
                                                           b_ctx, b_co, out_xo_logis);
}

// Round 8
// 526.745 us; speedup vs baseline: 1.8206x; 1.1964x over previous
//
#include <hip/hip_runtime.h>
#include <hip/hip_bf16.h>
#include <hip/hip_fp16.h>

#define N_NODES 50000
#define N_EDGES 800000
#define ET (N_EDGES + N_NODES)   // edges + self loops = 850000
#define IN_DIM 128
#define F1 256                   // H1*HID
#define H1 4
#define HID 64
#define H2 2
#define OUTC 8
#define F2 16                    // H2*OUTC
#define NB_SCAN ((N_NODES + 255) / 256)  // 196 scan blocks

typedef unsigned short u16;
typedef unsigned int u32;

static __device__ __forceinline__ float lrelu(float x) { return x > 0.f ? x : 0.2f * x; }
static __device__ __forceinline__ float eluf(float x) { return x > 0.f ? x : __expf(x) - 1.f; }
static __device__ __forceinline__ u16 f2h(float x) {
    __half h = __float2half(x);
    return *reinterpret_cast<u16*>(&h);
}

// ---------------- CSR build ----------------
__global__ void zero_kernel(int* p, int n) {
    int i = blockIdx.x * blockDim.x + threadIdx.x;
    if (i < n) p[i] = 0;
}

// edge_index arrives as int32 (harness converts integer inputs to int32).
__global__ void hist_kernel(const int* __restrict__ ei, int* __restrict__ deg) {
    int e = blockIdx.x * blockDim.x + threadIdx.x;
    if (e >= ET) return;
    int dst = (e < N_EDGES) ? ei[N_EDGES + e] : (e - N_EDGES);
    atomicAdd(&deg[dst], 1);
}

// two-level parallel exclusive scan: blockscan -> bsum_scan -> add_off
__global__ __launch_bounds__(256) void blockscan_kernel(const int* __restrict__ cnt,
                                                        int* __restrict__ off,
                                                        int* __restrict__ bsum) {
    int t = threadIdx.x;
    int b = blockIdx.x;
    int idx = b * 256 + t;
    int lane = t & 63, wv = t >> 6;
    int val = (idx < N_NODES) ? cnt[idx] : 0;
    int s = val;
#pragma unroll
    for (int d = 1; d < 64; d <<= 1) {
        int v2 = __shfl_up(s, d);
        if (lane >= d) s += v2;
    }
    __shared__ int wsum[4];
    if (lane == 63) wsum[wv] = s;
    __syncthreads();
    int prefix = 0;
#pragma unroll
    for (int i = 0; i < 3; i++) prefix += (i < wv) ? wsum[i] : 0;
    s += prefix;                           // inclusive within block
    if (idx < N_NODES) off[idx] = s - val; // exclusive partial
    if (t == 255) bsum[b] = s;             // block total
}

__global__ __launch_bounds__(256) void bsum_scan_kernel(int* __restrict__ bsum,
                                                        int* __restrict__ off) {
    int t = threadIdx.x;
    int lane = t & 63, wv = t >> 6;
    int val = (t < NB_SCAN) ? bsum[t] : 0;
    int s = val;
#pragma unroll
    for (int d = 1; d < 64; d <<= 1) {
        int v2 = __shfl_up(s, d);
        if (lane >= d) s += v2;
    }
    __shared__ int wsum[4];
    if (lane == 63) wsum[wv] = s;
    __syncthreads();
    int prefix = 0;
#pragma unroll
    for (int i = 0; i < 3; i++) prefix += (i < wv) ? wsum[i] : 0;
    s += prefix;                           // inclusive
    if (t < NB_SCAN) bsum[t] = s - val;    // exclusive block offset
    if (t == 255) off[N_NODES] = s;        // total = ET
}

__global__ __launch_bounds__(256) void add_off_kernel(int* __restrict__ off,
                                                      const int* __restrict__ bsum,
                                                      int* __restrict__ cursor) {
    int idx = blockIdx.x * 256 + threadIdx.x;
    if (idx >= N_NODES) return;
    int f = off[idx] + bsum[blockIdx.x];
    off[idx] = f;
    cursor[idx] = f;
}

__global__ void scatter_kernel(const int* __restrict__ ei, int* __restrict__ cursor,
                               int* __restrict__ csr_src) {
    int e = blockIdx.x * blockDim.x + threadIdx.x;
    if (e >= ET) return;
    int src, dst;
    if (e < N_EDGES) {
        src = ei[e];
        dst = ei[N_EDGES + e];
    } else {
        src = dst = e - N_EDGES;
    }
    int pos = atomicAdd(&cursor[dst], 1);
    csr_src[pos] = src;
}

// ---------------- tiny: interleave 2nd-level weights into WTi[k4][64][4] ----------------
// col c: 0..15 obj, 16..31 ctx, 32..47 co, 48..49 mlp, 50..63 zero-pad.
__global__ void wt_kernel(const float* __restrict__ W_obj, const float* __restrict__ W_ctx,
                          const float* __restrict__ W_co, const float* __restrict__ W_mlp,
                          float* __restrict__ WTi) {
    int t = blockIdx.x * blockDim.x + threadIdx.x;
    if (t >= 64 * 256) return;
    int c = t >> 8;
    int k = t & 255;
    float v = 0.f;
    if (c < 16) v = W_obj[k * 16 + c];
    else if (c < 32) v = W_ctx[k * 16 + (c - 16)];
    else if (c < 48) v = W_co[k * 16 + (c - 32)];
    else if (c < 50) v = W_mlp[k * 2 + (c - 48)];
    WTi[(k >> 2) * 256 + c * 4 + (k & 3)] = v;
}

// ---------------- GEMM1: h_lin = x @ W_feat (fp32 compute), store fp16 interleaved ----------------
// h_fp layout: [node][64 channels][4 heads] fp16  -> per lane one uint2 gather in conv1.
__global__ __launch_bounds__(256) void gemm1_kernel(const float* __restrict__ x,
                                                    const float* __restrict__ Wf,
                                                    const float* __restrict__ a_src,
                                                    const float* __restrict__ a_dst,
                                                    u16* __restrict__ h_fp,
                                                    float* __restrict__ al_s,
                                                    float* __restrict__ al_d) {
    __shared__ float xt[32 * 128];  // 16 KB; reused as fp16 staging (8192 u16) later
    int tid = threadIdx.x;
    int node0 = blockIdx.x * 32;
    const float4* xg = reinterpret_cast<const float4*>(x) + (size_t)node0 * 32;
    float4* xt4 = reinterpret_cast<float4*>(xt);
    int maxf4 = (N_NODES - node0) * 32;
#pragma unroll
    for (int i = 0; i < 4; i++) {
        int f4 = tid + i * 256;
        float4 v = make_float4(0.f, 0.f, 0.f, 0.f);
        if (f4 < maxf4) v = xg[f4];
        xt4[f4] = v;
    }
    __syncthreads();

    float acc[32];
#pragma unroll
    for (int r = 0; r < 32; r++) acc[r] = 0.f;
    int j = tid;
    for (int kc = 0; kc < 128; kc += 8) {
        float w[8];
#pragma unroll
        for (int kk = 0; kk < 8; kk++) w[kk] = Wf[(kc + kk) * 256 + j];
#pragma unroll
        for (int r = 0; r < 32; r++) {
            float4 a0 = xt4[r * 32 + (kc >> 2)];
            float4 a1 = xt4[r * 32 + (kc >> 2) + 1];
            acc[r] += a0.x * w[0] + a0.y * w[1] + a0.z * w[2] + a0.w * w[3] +
                      a1.x * w[4] + a1.y * w[5] + a1.z * w[6] + a1.w * w[7];
        }
    }

    // alpha reductions (register-only): wave w == head w
    {
        int head = tid >> 6;
        int lane = tid & 63;
        float asv = a_src[head * 64 + lane];
        float adv = a_dst[head * 64 + lane];
        for (int r = 0; r < 32; r++) {
            float ps = acc[r] * asv;
            float pd = acc[r] * adv;
#pragma unroll
            for (int d = 1; d < 64; d <<= 1) {
                ps += __shfl_xor(ps, d);
                pd += __shfl_xor(pd, d);
            }
            int node = node0 + r;
            if (lane == 0 && node < N_NODES) {
                al_s[node * 4 + head] = ps;
                al_d[node * 4 + head] = pd;
            }
        }
    }

    // fp16 transpose-staging in LDS: [r][ch][head] u16, then coalesced uint2 copy-out
    __syncthreads();  // done reading xt
    u16* hs = reinterpret_cast<u16*>(xt);
    int headj = tid >> 6, chj = tid & 63;
#pragma unroll
    for (int r = 0; r < 32; r++) hs[r * 256 + chj * 4 + headj] = f2h(acc[r]);
    __syncthreads();
    uint2* hq = reinterpret_cast<uint2*>(h_fp);
    const uint2* hsq = reinterpret_cast<const uint2*>(hs);
#pragma unroll
    for (int it = 0; it < 8; it++) {
        int idx = it * 256 + tid;            // uint2 index within block tile (2048 total)
        int node_local = idx >> 6;           // 64 uint2 per node
        if (node0 + node_local < N_NODES) hq[(size_t)node0 * 64 + idx] = hsq[idx];
    }
}

// ---------------- conv1 aggregation: one wave per dst node ----------------
__global__ __launch_bounds__(256) void conv1_aggregate(const int* __restrict__ deg_off,
                                                       const int* __restrict__ csr_src,
                                                       const u16* __restrict__ h_fp,
                                                       const float* __restrict__ al_s,
                                                       const float* __restrict__ al_d,
                                                       const float* __restrict__ b_feat,
                                                       float* __restrict__ h1) {
    int wave = threadIdx.x >> 6;
    int lane = threadIdx.x & 63;
    int node = blockIdx.x * 4 + wave;
    if (node >= N_NODES) return;
    int beg = deg_off[node], end = deg_off[node + 1];
    float4 aldv = *reinterpret_cast<const float4*>(al_d + node * 4);
    const uint2* hq = reinterpret_cast<const uint2*>(h_fp);
    float acc0 = 0.f, acc1 = 0.f, acc2 = 0.f, acc3 = 0.f;
    float s0 = 0.f, s1 = 0.f, s2 = 0.f, s3 = 0.f;

    int k = beg;
    for (; k + 4 <= end; k += 4) {
        int sa = csr_src[k], sb = csr_src[k + 1], sc = csr_src[k + 2], sd = csr_src[k + 3];
        float4 Aa = *reinterpret_cast<const float4*>(al_s + sa * 4);
        float4 Ab = *reinterpret_cast<const float4*>(al_s + sb * 4);
        float4 Ac = *reinterpret_cast<const float4*>(al_s + sc * 4);
        float4 Ad = *reinterpret_cast<const float4*>(al_s + sd * 4);
        uint2 ha = hq[(size_t)sa * 64 + lane];
        uint2 hb = hq[(size_t)sb * 64 + lane];
        uint2 hc = hq[(size_t)sc * 64 + lane];
        uint2 hd = hq[(size_t)sd * 64 + lane];
#define C1_EDGE(A, h)                                                        \
        {                                                                    \
            float p0 = __expf(lrelu(A.x + aldv.x));                          \
            float p1 = __expf(lrelu(A.y + aldv.y));                          \
            float p2 = __expf(lrelu(A.z + aldv.z));                          \
            float p3 = __expf(lrelu(A.w + aldv.w));                          \
            s0 += p0; s1 += p1; s2 += p2; s3 += p3;                          \
            __half2 q01 = *reinterpret_cast<const __half2*>(&h.x);           \
            __half2 q23 = *reinterpret_cast<const __half2*>(&h.y);           \
            acc0 += p0 * __low2float(q01);                                   \
            acc1 += p1 * __high2float(q01);                                  \
            acc2 += p2 * __low2float(q23);                                   \
            acc3 += p3 * __high2float(q23);                                  \
        }
        C1_EDGE(Aa, ha)
        C1_EDGE(Ab, hb)
        C1_EDGE(Ac, hc)
        C1_EDGE(Ad, hd)
    }
    for (; k < end; k++) {
        int sa = csr_src[k];
        float4 Aa = *reinterpret_cast<const float4*>(al_s + sa * 4);
        uint2 ha = hq[(size_t)sa * 64 + lane];
        C1_EDGE(Aa, ha)
    }
#undef C1_EDGE
    h1[(size_t)node * 256 + 0 * 64 + lane] = eluf(acc0 / (s0 + 1e-16f) + b_feat[0 * 64 + lane]);
    h1[(size_t)node * 256 + 1 * 64 + lane] = eluf(acc1 / (s1 + 1e-16f) + b_feat[1 * 64 + lane]);
    h1[(size_t)node * 256 + 2 * 64 + lane] = eluf(acc2 / (s2 + 1e-16f) + b_feat[2 * 64 + lane]);
    h1[(size_t)node * 256 + 3 * 64 + lane] = eluf(acc3 / (s3 + 1e-16f) + b_feat[3 * 64 + lane]);
}

// ---------------- phase B v4: h tile staged in LDS; lane=column (coalesced W) ----------------
// dots[r][c]: c 0..47 conv cols (obj/ctx/co x16), 48..49 mlp logits, 50..51 a0/a1.
__global__ __launch_bounds__(256) void phaseB_kernel(
    const float* __restrict__ h1, const float* __restrict__ WTi, const float* __restrict__ b_mlp,
    const float* __restrict__ as_obj, const float* __restrict__ ad_obj,
    const float* __restrict__ as_ctx, const float* __restrict__ ad_ctx,
    const float* __restrict__ as_co, const float* __restrict__ ad_co,
    u32* __restrict__ pack2, float* __restrict__ ald2,
    float* __restrict__ out_xo, float* __restrict__ out_xc) {
    __shared__ float hts[32 * 256];  // 32 KB h tile
    __shared__ float dots[32][52];   // 6.6 KB
    int tid = threadIdx.x;
    int node0 = blockIdx.x * 32;
    int lane = tid & 63;   // column
    int rg = tid >> 6;     // wave: nodes rg*8 .. rg*8+7
    const float4* WTi4 = reinterpret_cast<const float4*>(WTi);
    const float4* hg = reinterpret_cast<const float4*>(h1) + (size_t)node0 * 64;
    float4* hts4 = reinterpret_cast<float4*>(hts);

    // stage h tile: fully coalesced, 8 independent float4 loads per thread
    int maxf4 = (N_NODES - node0) * 64;
#pragma unroll
    for (int i = 0; i < 8; i++) {
        int idx = tid + i * 256;  // 0..2047
        float4 v = make_float4(0.f, 0.f, 0.f, 0.f);
        if (idx < maxf4) v = hg[idx];
        hts4[idx] = v;
    }
    __syncthreads();

    float accd[8];
#pragma unroll
    for (int r = 0; r < 8; r++) accd[r] = 0.f;
#pragma unroll 2
    for (int k4 = 0; k4 < 64; k4++) {
        float4 wv = WTi4[k4 * 64 + lane];           // coalesced 1KB/wave, L1/L2-hot
#pragma unroll
        for (int r = 0; r < 8; r++) {
            float4 hv = hts4[(rg * 8 + r) * 64 + k4];  // LDS broadcast (uniform addr)
            accd[r] += hv.x * wv.x + hv.y * wv.y + hv.z * wv.z + hv.w * wv.w;
        }
    }
    if (lane < 50) {
#pragma unroll
        for (int r = 0; r < 8; r++) dots[rg * 8 + r][lane] = accd[r];
    }
    __syncthreads();

    // epilogue A: node_att softmax (32 threads)
    if (tid < 32) {
        int r = tid;
        float l0 = dots[r][48] + b_mlp[0];
        float l1 = dots[r][49] + b_mlp[1];
        float mx = fmaxf(l0, l1);
        float e0 = __expf(l0 - mx), e1 = __expf(l1 - mx);
        float inv = 1.f / (e0 + e1);
        dots[r][50] = e0 * inv;
        dots[r][51] = e1 * inv;
    }
    __syncthreads();

    // epilogue B: 8 threads per node -> fp16 pack (3 words each) + alpha sums (j<6)
    {
        int r = tid >> 3, j = tid & 7;
        int node = node0 + r;
        if (node < N_NODES) {
            float a0 = dots[r][50], a1 = dots[r][51];
            u32* pb = pack2 + (size_t)node * 32;
#pragma unroll
            for (int wi = 0; wi < 3; wi++) {
                int w = j + wi * 8;        // word 0..23
                int c0 = 2 * w;
                int v = c0 >> 4;
                float scale = (v == 0) ? a0 : ((v == 1) ? a1 : 1.f);
                float g0 = dots[r][c0] * scale;
                float g1 = dots[r][c0 + 1] * scale;
                __half2 hh = __halves2half2(__float2half(g0), __float2half(g1));
                pb[w] = *reinterpret_cast<u32*>(&hh);
            }
            if (j < 6) {
                int v = j >> 1, head = j & 1;
                float scale = (v == 0) ? a0 : ((v == 1) ? a1 : 1.f);
                const float* asp = (v == 0) ? as_obj : ((v == 1) ? as_ctx : as_co);
                const float* adp = (v == 0) ? ad_obj : ((v == 1) ? ad_ctx : ad_co);
                float ss = 0.f, dd = 0.f;
#pragma unroll
                for (int i = 0; i < 8; i++) {
                    float g = dots[r][v * 16 + head * 8 + i] * scale;
                    ss += g * asp[head * 8 + i];
                    dd += g * adp[head * 8 + i];
                }
                pb[24 + j] = __float_as_uint(ss);
                ald2[(size_t)node * 8 + j] = dd;
            }
        }
    }
    __syncthreads();

    // epilogue C: elu outputs from LDS, float4 coalesced writes
    {
#pragma unroll
        for (int i = 0; i < 8; i++) {
            int idx = tid + i * 256;       // 0..2047
            int r = idx >> 6, c4 = idx & 63;
            int node = node0 + r;
            if (node < N_NODES) {
                float4 hv = hts4[idx];
                float a0 = dots[r][50], a1 = dots[r][51];
                float4 xo4 = make_float4(eluf(a0 * hv.x), eluf(a0 * hv.y),
                                         eluf(a0 * hv.z), eluf(a0 * hv.w));
                float4 xc4 = make_float4(eluf(a1 * hv.x), eluf(a1 * hv.y),
                                         eluf(a1 * hv.z), eluf(a1 * hv.w));
                reinterpret_cast<float4*>(out_xo + (size_t)node * 256)[c4] = xo4;
                reinterpret_cast<float4*>(out_xc + (size_t)node * 256)[c4] = xc4;
            }
        }
    }
}

// ---------------- fused conv2 aggregation (obj/ctx/co) ----------------
// one wave per dst node; lane = v*16 + head*8 + c (lanes 48..63 duplicate v=2, no writes)
__global__ __launch_bounds__(256) void conv2_aggregate(const int* __restrict__ deg_off,
                                                       const int* __restrict__ csr_src,
                                                       const u32* __restrict__ pack2,
                                                       const float* __restrict__ ald2,
                                                       const float* __restrict__ b_obj,
                                                       const float* __restrict__ b_ctx,
                                                       const float* __restrict__ b_co,
                                                       float* __restrict__ out) {
    int wave = threadIdx.x >> 6;
    int lane = threadIdx.x & 63;
    int node = blockIdx.x * 4 + wave;
    if (node >= N_NODES) return;
    int v = lane >> 4;
    if (v > 2) v = 2;
    int head = (lane >> 3) & 1;
    int c = lane & 7;
    int aidx = v * 2 + head;
    int gword = (v * 16 + head * 8 + c) >> 1;
    int ghi = c & 1;  // which half of the u32
    const float* bb = (v == 0) ? b_obj : (v == 1) ? b_ctx : b_co;
    float ald = ald2[(size_t)node * 8 + aidx];
    int beg = deg_off[node], end = deg_off[node + 1];
    float acc = 0.f, s = 0.f;
    int k = beg;
#define C2_EDGE(sx)                                                              \
    {                                                                            \
        const u32* pb = pack2 + (size_t)(sx) * 32;                               \
        u32 gw = pb[gword];                                                      \
        float als = __uint_as_float(pb[24 + aidx]);                              \
        __half2 gh = *reinterpret_cast<const __half2*>(&gw);                     \
        float g = ghi ? __high2float(gh) : __low2float(gh);                      \
        float p = __expf(lrelu(als + ald));                                      \
        s += p;                                                                  \
        acc += p * g;                                                            \
    }
    for (; k + 4 <= end; k += 4) {
        int sa = csr_src[k], sb = csr_src[k + 1], sc = csr_src[k + 2], sd = csr_src[k + 3];
        C2_EDGE(sa)
        C2_EDGE(sb)
        C2_EDGE(sc)
        C2_EDGE(sd)
    }
    for (; k < end; k++) {
        int sa = csr_src[k];
        C2_EDGE(sa)
    }
#undef C2_EDGE
    float o = acc / (s + 1e-16f);
    float mean = 0.5f * (o + __shfl_xor(o, 8)) + bb[c];
    float mx = mean;
#pragma unroll
    for (int d = 1; d < 8; d <<= 1) mx = fmaxf(mx, __shfl_xor(mx, d));
    float ex = __expf(mean - mx);
    float ss = ex;
#pragma unroll
    for (int d = 1; d < 8; d <<= 1) ss += __shfl_xor(ss, d);
    float res = (mean - mx) - __logf(ss);
    if (lane < 48 && head == 0) out[(size_t)v * (N_NODES * 8) + node * 8 + c] = res;
}

// ---------------- launch ----------------
extern "C" void kernel_launch(void* const* d_in, const int* in_sizes, int n_in, void* d_out,
                              int out_size, void* d_ws, size_t ws_size, hipStream_t stream) {
    const float* x = (const float*)d_in[0];
    const int* ei = (const int*)d_in[1];  // int64 in reference -> int32 from harness
    const float* W_feat = (const float*)d_in[2];
    const float* a_src_feat = (const float*)d_in[3];
    const float* a_dst_feat = (const float*)d_in[4];
    const float* b_feat = (const float*)d_in[5];
    const float* W_mlp = (const float*)d_in[6];
    const float* b_mlp = (const float*)d_in[7];
    const float* W_obj = (const float*)d_in[8];
    const float* as_obj = (const float*)d_in[9];
    const float* ad_obj = (const float*)d_in[10];
    const float* b_obj = (const float*)d_in[11];
    const float* W_ctx = (const float*)d_in[12];
    const float* as_ctx = (const float*)d_in[13];
    const float* ad_ctx = (const float*)d_in[14];
    const float* b_ctx = (const float*)d_in[15];
    const float* W_co = (const float*)d_in[16];
    const float* as_co = (const float*)d_in[17];
    const float* ad_co = (const float*)d_in[18];
    const float* b_co = (const float*)d_in[19];
    float* out = (float*)d_out;

    char* w = (char*)d_ws;
    auto alloc = [&](size_t bytes) {
        void* p = (void*)w;
        w += (bytes + 255) & ~(size_t)255;
        return p;
    };
    int* cursor = (int*)alloc((size_t)N_NODES * 4);
    int* deg_off = (int*)alloc((size_t)(N_NODES + 1) * 4);
    int* csr_src = (int*)alloc((size_t)ET * 4);
    int* bsum = (int*)alloc((size_t)NB_SCAN * 4);
    u16* h_fp = (u16*)alloc((size_t)N_NODES * 256 * 2);
    float* al_s1 = (float*)alloc((size_t)N_NODES * 4 * 4);
    float* al_d1 = (float*)alloc((size_t)N_NODES * 4 * 4);
    float* h1 = (float*)alloc((size_t)N_NODES * 256 * 4);
    float* WTi = (float*)alloc((size_t)64 * 256 * 4);
    u32* pack2 = (u32*)alloc((size_t)N_NODES * 32 * 4);
    float* ald2 = (float*)alloc((size_t)N_NODES * 8 * 4);

    float* out_xo_logis = out;                       // [N,8] x3 convs
    float* out_xo = out + (size_t)3 * N_NODES * 8;   // [N,256]
    float* out_xc = out_xo + (size_t)N_NODES * 256;  // [N,256]

    // CSR build (parallel two-level scan)
    zero_kernel<<<(N_NODES + 255) / 256, 256, 0, stream>>>(cursor, N_NODES);
    hist_kernel<<<(ET + 255) / 256, 256, 0, stream>>>(ei, cursor);
    blockscan_kernel<<<NB_SCAN, 256, 0, stream>>>(cursor, deg_off, bsum);
    bsum_scan_kernel<<<1, 256, 0, stream>>>(bsum, deg_off);
    add_off_kernel<<<NB_SCAN, 256, 0, stream>>>(deg_off, bsum, cursor);
    scatter_kernel<<<(ET + 255) / 256, 256, 0, stream>>>(ei, cursor, csr_src);
    // weight interleave (independent of CSR)
    wt_kernel<<<64, 256, 0, stream>>>(W_obj, W_ctx, W_co, W_mlp, WTi);

    // conv1
    gemm1_kernel<<<(N_NODES + 31) / 32, 256, 0, stream>>>(x, W_feat, a_src_feat, a_dst_feat,
                                                          h_fp, al_s1, al_d1);
    conv1_aggregate<<<(N_NODES + 3) / 4, 256, 0, stream>>>(deg_off, csr_src, h_fp, al_s1, al_d1,
                                                           b_feat, h1);
    // phase B
    phaseB_kernel<<<(N_NODES + 31) / 32, 256, 0, stream>>>(
        h1, WTi, b_mlp, as_obj, ad_obj, as_ctx, ad_ctx, as_co, ad_co, pack2, ald2, out_xo, out_xc);
    // fused conv2 x3
    conv2_aggregate<<<(N_NODES + 3) / 4, 256, 0, stream>>>(deg_off, csr_src, pack2, ald2, b_obj,
                                                           b_ctx, b_co, out_xo_logis);
}